// Round 16
// baseline (247.619 us; speedup 1.0000x reference)
//
#include <hip/hip_runtime.h>

constexpr int T_ = 4, B_ = 32, N_ = 1024, D_ = 512, O_ = 512, OP_ = 256;
constexpr int M_ = T_ * B_ * N_;
constexpr unsigned CAP = 1u * 1024 * 1024;

// ---- ws layout (bytes) ----
constexpr size_t WS_CNT  = 0;
constexpr size_t WS_WP   = 1u << 20;                  // 1 MiB fragment-ordered W (hi+lo)
constexpr size_t WS_LIST = WS_WP + (1u << 20);
constexpr size_t WS_NEED = WS_LIST + (size_t)CAP * 4;

typedef __attribute__((ext_vector_type(8)))  short bf8;
typedef __attribute__((ext_vector_type(16))) float f16v;

union U2B { struct { uint2 a, b; } p; bf8 v; };

__device__ __forceinline__ unsigned cvtpk(float x0, float x1) {
    unsigned r;
    asm("v_cvt_pk_bf16_f32 %0, %1, %2" : "=v"(r) : "v"(x0), "v"(x1));
    return r;
}
__device__ __forceinline__ float hi_lo_f(unsigned u) { return __uint_as_float(u << 16); }
__device__ __forceinline__ float hi_hi_f(unsigned u) { return __uint_as_float(u & 0xffff0000u); }

// ---------------- W prep: 32x32-fragment-ordered hi/lo split + cnt reset ----------------
// chunk c = [panel:8][j:16][q:8][lane:64], 16B each; q = tm*4 + eo*2 + Kh.
// col = colblk*128 + half*64 + 2*(lane&31) + eo ; k = j*32 + Kh*16 + (lane>>5)*8 .. +8
__global__ __launch_bounds__(256) void k_wprep(const float* __restrict__ W,
                                               unsigned short* __restrict__ wp,
                                               unsigned* __restrict__ cnt)
{
    if (blockIdx.x == 0 && threadIdx.x == 0) *cnt = 0u;
    const int c = blockIdx.x * 256 + threadIdx.x;      // 0..65535
    const int lane = c & 63, q = (c >> 6) & 7, j = (c >> 9) & 15, panel = c >> 13;
    const int colblk = panel >> 1, half = panel & 1;
    const int tm = q >> 2, eo = (q >> 1) & 1, Kh = q & 1;
    const int col = colblk * 128 + half * 64 + 2 * (lane & 31) + eo;
    const int k0 = j * 32 + Kh * 16 + (lane >> 5) * 8;
    const float* src = W + (size_t)col * 512 + k0;
    const float4 v0 = *(const float4*)(src);
    const float4 v1 = *(const float4*)(src + 4);
    const float xs[8] = {v0.x, v0.y, v0.z, v0.w, v1.x, v1.y, v1.z, v1.w};
    unsigned o[4];
    #pragma unroll
    for (int p = 0; p < 4; ++p) {
        const unsigned hi = cvtpk(xs[2 * p], xs[2 * p + 1]);
        if (tm == 0) {
            o[p] = hi;
        } else {
            const float l0 = xs[2 * p] - hi_lo_f(hi);
            const float l1 = xs[2 * p + 1] - hi_hi_f(hi);
            o[p] = cvtpk(l0, l1);
        }
    }
    *(uint4*)(wp + (size_t)c * 8) = make_uint4(o[0], o[1], o[2], o[3]);
}

// -------- 2-term fused GEMM, 8 waves x (32 rows x 64 cols) --------
// h ~= xh*wh + xh*wm ; flag |v-1|<1e-2 (25 sigma) + f64 repair.
// 512 threads, 128x128 tile, K-step 32, LDS 16KB: [buf:2][row:128][64B] hi-only.
// ~110 regs/wave -> 4 waves/SIMD.
__global__ __launch_bounds__(512, 4) void k_gemm(
    const float* __restrict__ x, const unsigned short* __restrict__ wp,
    const float* __restrict__ gamma, const float* __restrict__ beta,
    const float* __restrict__ rmean, const float* __restrict__ rvar,
    float* __restrict__ out, unsigned* __restrict__ cnt, unsigned* __restrict__ list)
{
    extern __shared__ char lds[];
    const int tid  = threadIdx.x;
    const int lane = tid & 63;
    const int wid  = tid >> 6;                  // 0..7

    const int dd = blockIdx.x;                  // XCD-aware swizzle
    const int w  = (dd & 7) * 512 + (dd >> 3);
    const int colblk = w & 3, rowblk = w >> 2;
    const int c0  = colblk * 128;
    const int wr  = (wid >> 1) * 32;            // wave row-tile base (0/32/64/96)
    const int wc  = (wid & 1) * 64;             // wave col-half

    // ---- BN constants (per-lane col pair) ----
    const int cE = c0 + wc + 2 * (lane & 31);
    const int cO = cE + 1;
    const float invE = gamma[cE] / sqrtf(rvar[cE] + 1e-5f);
    const float addE = beta[cE] - rmean[cE] * invE;
    const float invO = gamma[cO] / sqrtf(rvar[cO] + 1e-5f);
    const float addO = beta[cO] - rmean[cO] * invO;
    asm volatile("s_waitcnt vmcnt(0)" ::: "memory");
    __builtin_amdgcn_sched_barrier(0);

    // ---- A staging map: thread -> (row r = tid>>2, k-octet q = tid&3) ----
    const int r_s = tid >> 2;                   // 0..127
    const int q_s = tid & 3;
    const int t_a  = r_s & 3;
    const int sl_a = r_s >> 2;
    const unsigned vA = (unsigned)(t_a * 32768 + rowblk * 32 + sl_a) * 2048u
                      + (unsigned)q_s * 32u;
    // write addr: logical 8B slot 2q -> physical (2q)^Xw, Xw = (r>>1)&7; slot 2q+1 = ^8
    const int Xw = (r_s >> 1) & 7;
    const int wA0 = r_s * 64 + (((2 * q_s) ^ Xw) << 3);

    // ---- A-fragment read addrs (Kh = 0,1): row = wr + (lane&31) ----
    int rA0, rA1;
    {
        const int qv = lane & 31, hs = lane >> 5;
        const int Xr = (qv >> 1) & 7;
        const int row = wr + qv;
        rA0 = row * 64 + (((0 + hs * 2) ^ Xr) << 3);
        rA1 = row * 64 + (((4 + hs * 2) ^ Xr) << 3);
    }

    // ---- B voffset base (fragment-ordered, coalesced) ----
    const int panel = colblk * 2 + (wid & 1);
    const unsigned vBb = ((unsigned)panel << 17) + (unsigned)lane * 16u;

    f16v accE = (f16v)0.0f, accO = (f16v)0.0f;

    float4 Aa[2], Ab[2];
    bf8 Bf[8];          // [Kh*4 + tm*2 + eo]
    bf8 ah[2];          // [Kh]

#define SCHED __builtin_amdgcn_sched_barrier(0)

#define ALOAD(AI, K)                                                              \
    do {                                                                          \
        asm volatile("global_load_dwordx4 %0, %1, %2 offset:%3"                   \
                     : "=v"(AI[0]) : "v"(vA), "s"(x), "n"((K)*128 + 0)  : "memory"); \
        asm volatile("global_load_dwordx4 %0, %1, %2 offset:%3"                   \
                     : "=v"(AI[1]) : "v"(vA), "s"(x), "n"((K)*128 + 16) : "memory"); \
    } while (0)

// load the 4 B frags (tm x eo) of K-half KH for step K
#define BGRP(KH, K)                                                               \
    do {                                                                          \
        const unsigned vk  = vBb + (unsigned)((K) * 8192 + (KH) * 1024);          \
        const unsigned vk2 = vk + 4096u;                                          \
        asm volatile("global_load_dwordx4 %0, %1, %2 offset:%3"                   \
                     : "=v"(Bf[(KH)*4 + 0]) : "v"(vk),  "s"(wp), "n"(0)    : "memory"); \
        asm volatile("global_load_dwordx4 %0, %1, %2 offset:%3"                   \
                     : "=v"(Bf[(KH)*4 + 1]) : "v"(vk),  "s"(wp), "n"(2048) : "memory"); \
        asm volatile("global_load_dwordx4 %0, %1, %2 offset:%3"                   \
                     : "=v"(Bf[(KH)*4 + 2]) : "v"(vk2), "s"(wp), "n"(0)    : "memory"); \
        asm volatile("global_load_dwordx4 %0, %1, %2 offset:%3"                   \
                     : "=v"(Bf[(KH)*4 + 3]) : "v"(vk2), "s"(wp), "n"(2048) : "memory"); \
    } while (0)

// read A hi-fragment ah[KH] from buf (J&1)
#define DSR1(J, KH, RA)                                                           \
    do {                                                                          \
        const char* bR = lds + ((J) & 1) * 8192;                                  \
        U2B t;                                                                    \
        t.p.a = *(const uint2*)(bR + (RA));                                       \
        t.p.b = *(const uint2*)(bR + ((RA) ^ 8));                                 \
        ah[KH] = t.v;                                                             \
    } while (0)

// convert this thread's 8 f32 -> 8 bf16 (hi), write 2x uint2 swizzled
#define CONVW(AC, BUF)                                                            \
    do {                                                                          \
        char* pw = lds + (BUF) * 8192;                                            \
        const unsigned q0 = cvtpk(AC[0].x, AC[0].y), q1 = cvtpk(AC[0].z, AC[0].w);\
        const unsigned q2 = cvtpk(AC[1].x, AC[1].y), q3 = cvtpk(AC[1].z, AC[1].w);\
        *(uint2*)(pw + wA0) = make_uint2(q0, q1);                                 \
        *(uint2*)(pw + (wA0 ^ 8)) = make_uint2(q2, q3);                           \
    } while (0)

// 8 MFMAs (32x32x16): K-half KH, both eo, 2 term-products (hh + hm)
#define MGRP(KH)                                                                  \
    do {                                                                          \
        accE = __builtin_amdgcn_mfma_f32_32x32x16_bf16(ah[KH], Bf[(KH)*4+0], accE, 0, 0, 0); \
        accO = __builtin_amdgcn_mfma_f32_32x32x16_bf16(ah[KH], Bf[(KH)*4+1], accO, 0, 0, 0); \
        accE = __builtin_amdgcn_mfma_f32_32x32x16_bf16(ah[KH], Bf[(KH)*4+2], accE, 0, 0, 0); \
        accO = __builtin_amdgcn_mfma_f32_32x32x16_bf16(ah[KH], Bf[(KH)*4+3], accO, 0, 0, 0); \
    } while (0)

#define PRIO1 __builtin_amdgcn_s_setprio(1)
#define PRIO0 __builtin_amdgcn_s_setprio(0)

// Ledger at ITER(J) top (J<=13): outstanding = {A(J+1):2, BKh0(J):4, BKh1(J):4} = 10.
// vmcnt(8) retires A(J+1); vmcnt(4) retires BKh0(J); after {A(J+2):2, BKh0(J+1):4}
// issued, vmcnt(6) retires BKh1(J).
#define ITER(J, ATGT, ACV)                                                        \
    do {                                                                          \
        SCHED;                                                                    \
        asm volatile("s_waitcnt vmcnt(8)" ::: "memory");     /* A(J+1) ready */   \
        asm volatile("s_waitcnt lgkmcnt(0)" ::: "memory");   /* drain own ds */   \
        __builtin_amdgcn_s_barrier();                                             \
        SCHED;                                                                    \
        DSR1(J, 0, rA0);                                                          \
        SCHED;                                                                    \
        asm volatile("s_waitcnt vmcnt(4)" ::: "memory");     /* BKh0(J) ready */  \
        SCHED;                                                                    \
        PRIO1; MGRP(0); PRIO0;                                                    \
        SCHED;                                                                    \
        DSR1(J, 1, rA1);                                                          \
        if ((J) + 2 <= 15) { ALOAD(ATGT, (J) + 2); }                              \
        BGRP(0, (J) + 1);                                                         \
        SCHED;                                                                    \
        asm volatile("s_waitcnt vmcnt(6)" ::: "memory");     /* BKh1(J) ready */  \
        SCHED;                                                                    \
        PRIO1; MGRP(1); PRIO0;                                                    \
        SCHED;                                                                    \
        CONVW(ACV, ((J) + 1) & 1);                           /* off crit path */  \
        SCHED;                                                                    \
        BGRP(1, (J) + 1);                                                         \
        SCHED;                                                                    \
    } while (0)

    // ---- prologue: A(0),A(1),B(0); retire A0; conv A0 -> buf0 ----
    SCHED;
    ALOAD(Aa, 0);
    ALOAD(Ab, 1);
    SCHED;
    BGRP(0, 0);
    BGRP(1, 0);
    SCHED;
    asm volatile("s_waitcnt vmcnt(10)" ::: "memory");   // retire A(0)
    SCHED;
    CONVW(Aa, 0);
    SCHED;

    ITER(0,  Aa, Ab);
    ITER(1,  Ab, Aa);
    ITER(2,  Aa, Ab);
    ITER(3,  Ab, Aa);
    ITER(4,  Aa, Ab);
    ITER(5,  Ab, Aa);
    ITER(6,  Aa, Ab);
    ITER(7,  Ab, Aa);
    ITER(8,  Aa, Ab);
    ITER(9,  Ab, Aa);
    ITER(10, Aa, Ab);
    ITER(11, Ab, Aa);
    ITER(12, Aa, Ab);
    ITER(13, Ab, Aa);

    // ---- J = 14: no ALOAD; conv A15 (in Ab); top = {A15:2, BKh0(14):4, BKh1(14):4} ----
    SCHED;
    asm volatile("s_waitcnt vmcnt(8)" ::: "memory");    // retire A15
    asm volatile("s_waitcnt lgkmcnt(0)" ::: "memory");
    __builtin_amdgcn_s_barrier();
    SCHED;
    DSR1(14, 0, rA0);
    SCHED;
    asm volatile("s_waitcnt vmcnt(4)" ::: "memory");    // BKh0(14) ready
    SCHED;
    PRIO1; MGRP(0); PRIO0;
    SCHED;
    DSR1(14, 1, rA1);
    BGRP(0, 15);
    SCHED;
    asm volatile("s_waitcnt vmcnt(4)" ::: "memory");    // BKh1(14) ready
    SCHED;
    PRIO1; MGRP(1); PRIO0;
    SCHED;
    CONVW(Ab, 1);
    SCHED;
    BGRP(1, 15);
    SCHED;

    // ---- J = 15: tail; outstanding = {BKh0(15):4, BKh1(15):4} ----
    asm volatile("s_waitcnt lgkmcnt(0)" ::: "memory");
    __builtin_amdgcn_s_barrier();
    SCHED;
    DSR1(15, 0, rA0);
    SCHED;
    asm volatile("s_waitcnt vmcnt(4)" ::: "memory");    // BKh0(15) ready
    SCHED;
    PRIO1; MGRP(0); PRIO0;
    SCHED;
    DSR1(15, 1, rA1);
    SCHED;
    asm volatile("s_waitcnt vmcnt(0)" ::: "memory");    // BKh1(15) ready
    SCHED;
    PRIO1; MGRP(1); PRIO0;
    SCHED;

#undef ITER
#undef PRIO1
#undef PRIO0
#undef MGRP
#undef DSR1
#undef CONVW
#undef BGRP
#undef ALOAD
#undef SCHED

    // ---- epilogue: BN -> pool -> LIF, flag near-threshold pipelines (25-sigma) ----
    // C layout (32x32): col = lane&31 (E even / O odd), row = (reg&3) + 8*(reg>>2) + 4*(lane>>5).
    const int opL = ((c0 + wc) >> 1) + (lane & 31);
    #pragma unroll
    for (int g = 0; g < 4; ++g) {
        const int site = rowblk * 32 + (wid >> 1) * 8 + 2 * g + (lane >> 5);
        const int bI = site >> 10, nI = site & 1023;
        float v = 0.0f;
        bool flg = false;
        #pragma unroll
        for (int t = 0; t < 4; ++t) {
            const float hE = accE[g * 4 + t] * invE + addE;
            const float hO = accO[g * 4 + t] * invO + addO;
            const float m = fmaxf(hE, hO);
            v = (v + m) * 0.5f;
            const float dv = v - 1.0f;
            const bool sp = dv >= 0.0f;
            out[(((size_t)t * 32 + bI) * 1024 + nI) * 256 + opL] = sp ? 1.0f : 0.0f;
            flg |= (fabsf(dv) < 1e-2f);
            if (sp) v = 0.0f;
        }
        if (flg) {
            unsigned idx = atomicAdd(cnt, 1u);
            if (idx < CAP) list[idx] = ((unsigned)site << 8) | (unsigned)opL;
        }
    }
}

// ---------------- exact f64 repair, wave-parallel (1 wave per flagged pipeline) ----------
__global__ __launch_bounds__(256) void k_repair(
    const float* __restrict__ x, const float* __restrict__ W,
    const float* __restrict__ gamma, const float* __restrict__ beta,
    const float* __restrict__ rmean, const float* __restrict__ rvar,
    float* __restrict__ out, const unsigned* __restrict__ cnt,
    const unsigned* __restrict__ list)
{
    unsigned count = *cnt;
    if (count > CAP) count = CAP;
    const int lane = threadIdx.x & 63;
    const unsigned gw = (blockIdx.x * 256u + threadIdx.x) >> 6;   // global wave id
    const unsigned nw = (gridDim.x * 256u) >> 6;
    const int d0 = lane * 8;

    for (unsigned j = gw; j < count; j += nw) {
        const unsigned e = list[j];
        const int op = e & 255;
        const int site = e >> 8;
        const int bI = site >> 10, nI = site & 1023;

        double wv[2][8];
        #pragma unroll
        for (int p = 0; p < 2; ++p) {
            const float* Wr = W + (size_t)(2 * op + p) * D_ + d0;
            const float4 a = *(const float4*)(Wr);
            const float4 b = *(const float4*)(Wr + 4);
            wv[p][0] = a.x; wv[p][1] = a.y; wv[p][2] = a.z; wv[p][3] = a.w;
            wv[p][4] = b.x; wv[p][5] = b.y; wv[p][6] = b.z; wv[p][7] = b.w;
        }

        double h[4][2];
        #pragma unroll
        for (int t = 0; t < 4; ++t) {
            const float* xr = x + (((size_t)t * 32 + bI) * 1024 + nI) * D_ + d0;
            const float4 a = *(const float4*)(xr);
            const float4 b = *(const float4*)(xr + 4);
            const double xv[8] = {(double)a.x, (double)a.y, (double)a.z, (double)a.w,
                                  (double)b.x, (double)b.y, (double)b.z, (double)b.w};
            #pragma unroll
            for (int p = 0; p < 2; ++p) {
                double s0 = 0, s1 = 0, s2 = 0, s3 = 0;
                s0 = fma(xv[0], wv[p][0], s0); s1 = fma(xv[1], wv[p][1], s1);
                s2 = fma(xv[2], wv[p][2], s2); s3 = fma(xv[3], wv[p][3], s3);
                s0 = fma(xv[4], wv[p][4], s0); s1 = fma(xv[5], wv[p][5], s1);
                s2 = fma(xv[6], wv[p][6], s2); s3 = fma(xv[7], wv[p][7], s3);
                double s = (s0 + s1) + (s2 + s3);
                #pragma unroll
                for (int off = 32; off > 0; off >>= 1)
                    s += __shfl_xor(s, off, 64);
                h[t][p] = s;
            }
        }

        double iv[2], ad[2];
        #pragma unroll
        for (int p = 0; p < 2; ++p) {
            const int c = 2 * op + p;
            iv[p] = (double)gamma[c] / sqrt((double)rvar[c] + 1e-5);
            ad[p] = (double)beta[c] - (double)rmean[c] * iv[p];
        }
        double v = 0.0;
        #pragma unroll
        for (int t = 0; t < 4; ++t) {
            const double h0 = h[t][0] * iv[0] + ad[0];
            const double h1 = h[t][1] * iv[1] + ad[1];
            const double m = fmax(h0, h1);
            v = (v + m) * 0.5;
            const bool sp = (v >= 1.0);
            if (lane == t)
                out[(((size_t)t * 32 + bI) * 1024 + nI) * 256 + op] = sp ? 1.0f : 0.0f;
            if (sp) v = 0.0;
        }
    }
}

// ---------------- fallback (round-1 exact f64 kernel) ----------------
constexpr int FB_SITES = 32, FB_ROWS = 128, FB_BN = 64, FB_BK = 16;

__global__ __launch_bounds__(256)
void snn_fused_f64(const float* __restrict__ x, const float* __restrict__ W,
                   const float* __restrict__ gamma, const float* __restrict__ beta,
                   const float* __restrict__ rmean, const float* __restrict__ rvar,
                   float* __restrict__ out)
{
    __shared__ float As[FB_BK][FB_ROWS];
    __shared__ float Bs[FB_BK][FB_BN];
    const int tid = threadIdx.x;
    const int tx = tid & 15, ty = tid >> 4;
    const int c0 = blockIdx.x * FB_BN;
    const int site_base = blockIdx.y * FB_SITES;
    const int b = site_base / N_, n0 = site_base % N_;
    const int lrow = tid >> 1, lk = (tid & 1) * 8;
    const int s_l = lrow >> 2, t_l = lrow & 3;
    const float* xrow = x + (size_t)((t_l * B_ + b) * N_ + (n0 + s_l)) * D_ + lk;
    const int wc = tid & 63, wk = (tid >> 6) * 4;
    const float* wrow = W + (size_t)(c0 + wc) * D_ + wk;
    double acc[8][4];
    #pragma unroll
    for (int i = 0; i < 8; ++i)
        #pragma unroll
        for (int j = 0; j < 4; ++j) acc[i][j] = 0.0;
    for (int k0 = 0; k0 < D_; k0 += FB_BK) {
        const float4 a0 = *(const float4*)(xrow + k0);
        const float4 a1 = *(const float4*)(xrow + k0 + 4);
        const float4 w4 = *(const float4*)(wrow + k0);
        As[lk + 0][lrow] = a0.x; As[lk + 1][lrow] = a0.y; As[lk + 2][lrow] = a0.z; As[lk + 3][lrow] = a0.w;
        As[lk + 4][lrow] = a1.x; As[lk + 5][lrow] = a1.y; As[lk + 6][lrow] = a1.z; As[lk + 7][lrow] = a1.w;
        Bs[wk + 0][wc] = w4.x; Bs[wk + 1][wc] = w4.y; Bs[wk + 2][wc] = w4.z; Bs[wk + 3][wc] = w4.w;
        __syncthreads();
        #pragma unroll
        for (int k = 0; k < FB_BK; ++k) {
            const float4 af0 = *(const float4*)&As[k][ty * 8];
            const float4 af1 = *(const float4*)&As[k][ty * 8 + 4];
            const float4 bf = *(const float4*)&Bs[k][tx * 4];
            const double ad[8] = {(double)af0.x, (double)af0.y, (double)af0.z, (double)af0.w,
                                  (double)af1.x, (double)af1.y, (double)af1.z, (double)af1.w};
            const double bd[4] = {(double)bf.x, (double)bf.y, (double)bf.z, (double)bf.w};
            #pragma unroll
            for (int i = 0; i < 8; ++i)
                #pragma unroll
                for (int j = 0; j < 4; ++j) acc[i][j] = fma(ad[i], bd[j], acc[i][j]);
        }
        __syncthreads();
    }
    double invd[4], addd[4];
    #pragma unroll
    for (int j = 0; j < 4; ++j) {
        const int c = c0 + tx * 4 + j;
        const double ivv = (double)gamma[c] / sqrt((double)rvar[c] + 1e-5);
        invd[j] = ivv; addd[j] = (double)beta[c] - (double)rmean[c] * ivv;
    }
    #pragma unroll
    for (int si = 0; si < 2; ++si) {
        const int n = n0 + ty * 2 + si;
        #pragma unroll
        for (int p = 0; p < 2; ++p) {
            const int op = (c0 >> 1) + tx * 2 + p;
            double v = 0.0;
            #pragma unroll
            for (int t = 0; t < 4; ++t) {
                const int i = si * 4 + t;
                const double h0 = acc[i][2 * p] * invd[2 * p] + addd[2 * p];
                const double h1 = acc[i][2 * p + 1] * invd[2 * p + 1] + addd[2 * p + 1];
                const double m = fmax(h0, h1);
                v = v + (m - v) * 0.5;
                const bool sp = (v >= 1.0);
                out[((size_t)(t * B_ + b) * N_ + n) * OP_ + op] = sp ? 1.0f : 0.0f;
                if (sp) v = 0.0;
            }
        }
    }
}

extern "C" void kernel_launch(void* const* d_in, const int* in_sizes, int n_in,
                              void* d_out, int out_size, void* d_ws, size_t ws_size,
                              hipStream_t stream)
{
    const float* x     = (const float*)d_in[0];
    const float* W     = (const float*)d_in[1];
    const float* gamma = (const float*)d_in[2];
    const float* beta  = (const float*)d_in[3];
    const float* rmean = (const float*)d_in[4];
    const float* rvar  = (const float*)d_in[5];
    float* out = (float*)d_out;

    if (ws_size < WS_NEED) {
        dim3 grid(O_ / FB_BN, (B_ * N_) / FB_SITES);
        snn_fused_f64<<<grid, dim3(256), 0, stream>>>(x, W, gamma, beta, rmean, rvar, out);
        return;
    }

    char* ws = (char*)d_ws;
    unsigned* cnt = (unsigned*)(ws + WS_CNT);
    unsigned short* wp = (unsigned short*)(ws + WS_WP);
    unsigned* list = (unsigned*)(ws + WS_LIST);

    k_wprep<<<256, 256, 0, stream>>>(W, wp, cnt);
    k_gemm<<<4096, 512, 16384, stream>>>(x, wp, gamma, beta, rmean, rvar, out, cnt, list);
    k_repair<<<512, 256, 0, stream>>>(x, W, gamma, beta, rmean, rvar, out, cnt, list);
}

// Round 17
// 201.708 us; speedup vs baseline: 1.2276x; 1.2276x over previous
//
#include <hip/hip_runtime.h>

constexpr int T_ = 4, B_ = 32, N_ = 1024, D_ = 512, O_ = 512, OP_ = 256;
constexpr int M_ = T_ * B_ * N_;
constexpr unsigned CAP = 1u * 1024 * 1024;

// ---- ws layout (bytes) ----
constexpr size_t WS_CNT  = 0;
constexpr size_t WS_WP   = 1u << 20;                  // 1 MiB fragment-ordered W (hi+lo)
constexpr size_t WS_LIST = WS_WP + (1u << 20);
constexpr size_t WS_NEED = WS_LIST + (size_t)CAP * 4;

constexpr int RSTRIDE = 72;                           // padded LDS row stride (bytes)
constexpr int BUFSZ   = 128 * RSTRIDE;                // 9216 B per buffer

typedef __attribute__((ext_vector_type(8)))  short bf8;
typedef __attribute__((ext_vector_type(16))) float f16v;

union U2B { struct { uint2 a, b; } p; bf8 v; };

__device__ __forceinline__ unsigned cvtpk(float x0, float x1) {
    unsigned r;
    asm("v_cvt_pk_bf16_f32 %0, %1, %2" : "=v"(r) : "v"(x0), "v"(x1));
    return r;
}
__device__ __forceinline__ float hi_lo_f(unsigned u) { return __uint_as_float(u << 16); }
__device__ __forceinline__ float hi_hi_f(unsigned u) { return __uint_as_float(u & 0xffff0000u); }

// ---------------- W prep: 32x32-fragment-ordered hi/lo split + cnt reset ----------------
// chunk c = [panel:8][j:16][q:8][lane:64], 16B each; q = tm*4 + eo*2 + Kh.
// col = colblk*128 + half*64 + 2*(lane&31) + eo ; k = j*32 + Kh*16 + (lane>>5)*8 .. +8
__global__ __launch_bounds__(256) void k_wprep(const float* __restrict__ W,
                                               unsigned short* __restrict__ wp,
                                               unsigned* __restrict__ cnt)
{
    if (blockIdx.x == 0 && threadIdx.x == 0) *cnt = 0u;
    const int c = blockIdx.x * 256 + threadIdx.x;      // 0..65535
    const int lane = c & 63, q = (c >> 6) & 7, j = (c >> 9) & 15, panel = c >> 13;
    const int colblk = panel >> 1, half = panel & 1;
    const int tm = q >> 2, eo = (q >> 1) & 1, Kh = q & 1;
    const int col = colblk * 128 + half * 64 + 2 * (lane & 31) + eo;
    const int k0 = j * 32 + Kh * 16 + (lane >> 5) * 8;
    const float* src = W + (size_t)col * 512 + k0;
    const float4 v0 = *(const float4*)(src);
    const float4 v1 = *(const float4*)(src + 4);
    const float xs[8] = {v0.x, v0.y, v0.z, v0.w, v1.x, v1.y, v1.z, v1.w};
    unsigned o[4];
    #pragma unroll
    for (int p = 0; p < 4; ++p) {
        const unsigned hi = cvtpk(xs[2 * p], xs[2 * p + 1]);
        if (tm == 0) {
            o[p] = hi;
        } else {
            const float l0 = xs[2 * p] - hi_lo_f(hi);
            const float l1 = xs[2 * p + 1] - hi_hi_f(hi);
            o[p] = cvtpk(l0, l1);
        }
    }
    *(uint4*)(wp + (size_t)c * 8) = make_uint4(o[0], o[1], o[2], o[3]);
}

// -------- 2-term fused GEMM (32x32x16 MFMA, 72B-padded LDS rows) --------
// h ~= xh*wh + xh*wm ; flag |v-1|<1e-2 (25 sigma) + f64 repair.
// 4 waves, 128x128 tile, K-step 32, LDS 2 x 9216 B (hi only).
// Bank pairs: (9*row + slot) mod 16 -> uniform across every ds instruction.
__global__ __launch_bounds__(256, 3) void k_gemm(
    const float* __restrict__ x, const unsigned short* __restrict__ wp,
    const float* __restrict__ gamma, const float* __restrict__ beta,
    const float* __restrict__ rmean, const float* __restrict__ rvar,
    float* __restrict__ out, unsigned* __restrict__ cnt, unsigned* __restrict__ list)
{
    extern __shared__ char lds[];
    const int tid  = threadIdx.x;
    const int lane = tid & 63;
    const int wid  = tid >> 6;

    const int dd = blockIdx.x;                  // XCD-aware swizzle
    const int w  = (dd & 7) * 512 + (dd >> 3);
    const int colblk = w & 3, rowblk = w >> 2;
    const int c0  = colblk * 128;
    const int wr0 = (wid >> 1) * 64, wc0 = (wid & 1) * 64;

    // ---- BN constants (per-lane col pair) ----
    const int cE = c0 + wc0 + 2 * (lane & 31);
    const int cO = cE + 1;
    const float invE = gamma[cE] / sqrtf(rvar[cE] + 1e-5f);
    const float addE = beta[cE] - rmean[cE] * invE;
    const float invO = gamma[cO] / sqrtf(rvar[cO] + 1e-5f);
    const float addO = beta[cO] - rmean[cO] * invO;
    asm volatile("s_waitcnt vmcnt(0)" ::: "memory");
    __builtin_amdgcn_sched_barrier(0);

    // ---- A staging map (2 threads/row): arow 0..127, kh = 16-float half ----
    const int arow = tid >> 1;
    const int kh   = tid & 1;
    const int t_a  = arow & 3;
    const int sl_a = arow >> 2;
    const unsigned vA = (unsigned)(t_a * 32768 + rowblk * 32 + sl_a) * 2048u
                      + (unsigned)kh * 64u;
    // write addrs: slot j of this thread's 32B half-row (no swizzle; padding spreads banks)
    const int wA0 = arow * RSTRIDE + kh * 32;

    // ---- A-fragment read addrs: frag (rt,Kh): row = wr0+rt*32+(lane&31),
    //      bytes Kh*32 + hs*16 .. +15 (read as 2x uint2 at +0/+8) ----
    int rA00, rA01, rA10, rA11;
    {
        const int qv = lane & 31, hs = lane >> 5;
        const int r0 = wr0 + qv, r1 = wr0 + 32 + qv;
        rA00 = r0 * RSTRIDE + 0  + hs * 16;
        rA01 = r0 * RSTRIDE + 32 + hs * 16;
        rA10 = r1 * RSTRIDE + 0  + hs * 16;
        rA11 = r1 * RSTRIDE + 32 + hs * 16;
    }

    // ---- B voffset base (fragment-ordered, coalesced) ----
    const int panel = colblk * 2 + (wid & 1);
    const unsigned vBb = ((unsigned)panel << 17) + (unsigned)lane * 16u;

    f16v accE[2], accO[2];
    #pragma unroll
    for (int i = 0; i < 2; ++i) { accE[i] = (f16v)0.0f; accO[i] = (f16v)0.0f; }

    float4 Aa[4], Ab[4];
    bf8 Bf[8];          // [Kh*4 + tm*2 + eo]
    bf8 ah[4];          // [rt*2 + Kh]

#define SCHED __builtin_amdgcn_sched_barrier(0)

#define ALOAD(AI, K)                                                              \
    do {                                                                          \
        asm volatile("global_load_dwordx4 %0, %1, %2 offset:%3"                   \
                     : "=v"(AI[0]) : "v"(vA), "s"(x), "n"((K)*128 + 0)  : "memory"); \
        asm volatile("global_load_dwordx4 %0, %1, %2 offset:%3"                   \
                     : "=v"(AI[1]) : "v"(vA), "s"(x), "n"((K)*128 + 16) : "memory"); \
        asm volatile("global_load_dwordx4 %0, %1, %2 offset:%3"                   \
                     : "=v"(AI[2]) : "v"(vA), "s"(x), "n"((K)*128 + 32) : "memory"); \
        asm volatile("global_load_dwordx4 %0, %1, %2 offset:%3"                   \
                     : "=v"(AI[3]) : "v"(vA), "s"(x), "n"((K)*128 + 48) : "memory"); \
    } while (0)

// load the 4 B frags (tm x eo) of K-half KH for step K
#define BGRP(KH, K)                                                               \
    do {                                                                          \
        const unsigned vk  = vBb + (unsigned)((K) * 8192 + (KH) * 1024);          \
        const unsigned vk2 = vk + 4096u;                                          \
        asm volatile("global_load_dwordx4 %0, %1, %2 offset:%3"                   \
                     : "=v"(Bf[(KH)*4 + 0]) : "v"(vk),  "s"(wp), "n"(0)    : "memory"); \
        asm volatile("global_load_dwordx4 %0, %1, %2 offset:%3"                   \
                     : "=v"(Bf[(KH)*4 + 1]) : "v"(vk),  "s"(wp), "n"(2048) : "memory"); \
        asm volatile("global_load_dwordx4 %0, %1, %2 offset:%3"                   \
                     : "=v"(Bf[(KH)*4 + 2]) : "v"(vk2), "s"(wp), "n"(0)    : "memory"); \
        asm volatile("global_load_dwordx4 %0, %1, %2 offset:%3"                   \
                     : "=v"(Bf[(KH)*4 + 3]) : "v"(vk2), "s"(wp), "n"(2048) : "memory"); \
    } while (0)

// read one A hi-fragment ah[IDX] from buf (J&1) at addr RA (2x b64 at +0/+8)
#define DSR1(J, IDX, RA)                                                          \
    do {                                                                          \
        const char* bR = lds + ((J) & 1) * BUFSZ;                                 \
        U2B t;                                                                    \
        t.p.a = *(const uint2*)(bR + (RA));                                       \
        t.p.b = *(const uint2*)(bR + (RA) + 8);                                   \
        ah[IDX] = t.v;                                                            \
    } while (0)

// hi -> 4 consecutive 8B slots of this thread's 32B half-row
#define CONVW(AC, BUF)                                                            \
    do {                                                                          \
        char* pw = lds + (BUF) * BUFSZ + wA0;                                     \
        const unsigned q0 = cvtpk(AC[0].x, AC[0].y), q1 = cvtpk(AC[0].z, AC[0].w);\
        const unsigned q2 = cvtpk(AC[1].x, AC[1].y), q3 = cvtpk(AC[1].z, AC[1].w);\
        *(uint2*)(pw + 0)  = make_uint2(q0, q1);                                  \
        *(uint2*)(pw + 8)  = make_uint2(q2, q3);                                  \
        const unsigned q4 = cvtpk(AC[2].x, AC[2].y), q5 = cvtpk(AC[2].z, AC[2].w);\
        const unsigned q6 = cvtpk(AC[3].x, AC[3].y), q7 = cvtpk(AC[3].z, AC[3].w);\
        *(uint2*)(pw + 16) = make_uint2(q4, q5);                                  \
        *(uint2*)(pw + 24) = make_uint2(q6, q7);                                  \
    } while (0)

// 4 MFMAs (32x32x16): row-tile RT, K-half KH, both eo, 2 term-products (hh + hm)
#define MGRP4(KH, RT)                                                             \
    do {                                                                          \
        accE[RT] = __builtin_amdgcn_mfma_f32_32x32x16_bf16(ah[(RT)*2+(KH)], Bf[(KH)*4+0], accE[RT], 0, 0, 0); \
        accO[RT] = __builtin_amdgcn_mfma_f32_32x32x16_bf16(ah[(RT)*2+(KH)], Bf[(KH)*4+1], accO[RT], 0, 0, 0); \
        accE[RT] = __builtin_amdgcn_mfma_f32_32x32x16_bf16(ah[(RT)*2+(KH)], Bf[(KH)*4+2], accE[RT], 0, 0, 0); \
        accO[RT] = __builtin_amdgcn_mfma_f32_32x32x16_bf16(ah[(RT)*2+(KH)], Bf[(KH)*4+3], accO[RT], 0, 0, 0); \
    } while (0)

#define PRIO1 __builtin_amdgcn_s_setprio(1)
#define PRIO0 __builtin_amdgcn_s_setprio(0)

// Ledger at ITER(J) top (J<=13): outstanding = {A(J+1):4, BKh0(J):4, BKh1(J):4} = 12.
// vmcnt(8) retires A(J+1); vmcnt(4) retires BKh0(J); after {A(J+2):4, BKh0(J+1):4}
// issued, vmcnt(8) retires BKh1(J).
#define ITER(J, ATGT, ACV)                                                        \
    do {                                                                          \
        SCHED;                                                                    \
        asm volatile("s_waitcnt vmcnt(8)" ::: "memory");     /* A(J+1) ready */   \
        asm volatile("s_waitcnt lgkmcnt(0)" ::: "memory");   /* drain own ds */   \
        __builtin_amdgcn_s_barrier();                                             \
        SCHED;                                                                    \
        DSR1(J, 0, rA00);                                    /* frag (0,KH0) */   \
        SCHED;                                                                    \
        asm volatile("s_waitcnt vmcnt(4)" ::: "memory");     /* BKh0(J) ready */  \
        SCHED;                                                                    \
        PRIO1; MGRP4(0, 0); PRIO0;                                                \
        SCHED;                                                                    \
        DSR1(J, 2, rA10);                                    /* frag (1,KH0) */   \
        if ((J) + 2 <= 15) { ALOAD(ATGT, (J) + 2); }                              \
        SCHED;                                                                    \
        PRIO1; MGRP4(0, 1); PRIO0;                                                \
        SCHED;                                                                    \
        DSR1(J, 1, rA01);                                    /* frag (0,KH1) */   \
        DSR1(J, 3, rA11);                                    /* frag (1,KH1) */   \
        BGRP(0, (J) + 1);                                                         \
        SCHED;                                                                    \
        asm volatile("s_waitcnt vmcnt(8)" ::: "memory");     /* BKh1(J) ready */  \
        SCHED;                                                                    \
        PRIO1; MGRP4(1, 0); PRIO0;                                                \
        SCHED;                                                                    \
        CONVW(ACV, ((J) + 1) & 1);                           /* off crit path */  \
        SCHED;                                                                    \
        PRIO1; MGRP4(1, 1); PRIO0;                                                \
        SCHED;                                                                    \
        BGRP(1, (J) + 1);                                                         \
        SCHED;                                                                    \
    } while (0)

    // ---- prologue: A(0),A(1),B(0); retire A0; conv A0 -> buf0 ----
    SCHED;
    ALOAD(Aa, 0);
    ALOAD(Ab, 1);
    SCHED;
    BGRP(0, 0);
    BGRP(1, 0);
    SCHED;
    asm volatile("s_waitcnt vmcnt(12)" ::: "memory");   // retire A(0)
    SCHED;
    CONVW(Aa, 0);
    SCHED;

    ITER(0,  Aa, Ab);
    ITER(1,  Ab, Aa);
    ITER(2,  Aa, Ab);
    ITER(3,  Ab, Aa);
    ITER(4,  Aa, Ab);
    ITER(5,  Ab, Aa);
    ITER(6,  Aa, Ab);
    ITER(7,  Ab, Aa);
    ITER(8,  Aa, Ab);
    ITER(9,  Ab, Aa);
    ITER(10, Aa, Ab);
    ITER(11, Ab, Aa);
    ITER(12, Aa, Ab);
    ITER(13, Ab, Aa);

    // ---- J = 14: no ALOAD; conv A15 (in Ab); top = {A15:4, BKh0(14):4, BKh1(14):4} ----
    SCHED;
    asm volatile("s_waitcnt vmcnt(8)" ::: "memory");    // retire A15
    asm volatile("s_waitcnt lgkmcnt(0)" ::: "memory");
    __builtin_amdgcn_s_barrier();
    SCHED;
    DSR1(14, 0, rA00);
    SCHED;
    asm volatile("s_waitcnt vmcnt(4)" ::: "memory");    // BKh0(14) ready
    SCHED;
    PRIO1; MGRP4(0, 0); PRIO0;
    SCHED;
    DSR1(14, 2, rA10);
    SCHED;
    PRIO1; MGRP4(0, 1); PRIO0;
    SCHED;
    DSR1(14, 1, rA01);
    DSR1(14, 3, rA11);
    BGRP(0, 15);
    SCHED;
    asm volatile("s_waitcnt vmcnt(4)" ::: "memory");    // BKh1(14) ready
    SCHED;
    PRIO1; MGRP4(1, 0); PRIO0;
    SCHED;
    CONVW(Ab, 1);
    SCHED;
    PRIO1; MGRP4(1, 1); PRIO0;
    SCHED;
    BGRP(1, 15);
    SCHED;

    // ---- J = 15: tail; outstanding = {BKh0(15):4, BKh1(15):4} ----
    asm volatile("s_waitcnt lgkmcnt(0)" ::: "memory");
    __builtin_amdgcn_s_barrier();
    SCHED;
    DSR1(15, 0, rA00);
    DSR1(15, 2, rA10);
    SCHED;
    asm volatile("s_waitcnt vmcnt(4)" ::: "memory");    // BKh0(15) ready
    SCHED;
    PRIO1; MGRP4(0, 0); PRIO0;
    SCHED;
    DSR1(15, 1, rA01);
    DSR1(15, 3, rA11);
    SCHED;
    PRIO1; MGRP4(0, 1); PRIO0;
    SCHED;
    asm volatile("s_waitcnt vmcnt(0)" ::: "memory");    // BKh1(15) ready
    SCHED;
    PRIO1; MGRP4(1, 0); PRIO0;
    SCHED;
    PRIO1; MGRP4(1, 1); PRIO0;
    SCHED;

#undef ITER
#undef PRIO1
#undef PRIO0
#undef MGRP4
#undef DSR1
#undef CONVW
#undef BGRP
#undef ALOAD
#undef SCHED

    // ---- epilogue: BN -> pool -> LIF, flag near-threshold pipelines (25-sigma) ----
    // C layout (32x32): col = lane&31 (E even / O odd), row = (reg&3) + 8*(reg>>2) + 4*(lane>>5).
    const int opL = ((c0 + wc0) >> 1) + (lane & 31);
    #pragma unroll
    for (int rt = 0; rt < 2; ++rt) {
        #pragma unroll
        for (int g = 0; g < 4; ++g) {
            const int site = rowblk * 32 + (wid >> 1) * 16 + rt * 8 + 2 * g + (lane >> 5);
            const int bI = site >> 10, nI = site & 1023;
            float v = 0.0f;
            bool flg = false;
            #pragma unroll
            for (int t = 0; t < 4; ++t) {
                const float hE = accE[rt][g * 4 + t] * invE + addE;
                const float hO = accO[rt][g * 4 + t] * invO + addO;
                const float m = fmaxf(hE, hO);
                v = (v + m) * 0.5f;
                const float dv = v - 1.0f;
                const bool sp = dv >= 0.0f;
                out[(((size_t)t * 32 + bI) * 1024 + nI) * 256 + opL] = sp ? 1.0f : 0.0f;
                flg |= (fabsf(dv) < 1e-2f);
                if (sp) v = 0.0f;
            }
            if (flg) {
                unsigned idx = atomicAdd(cnt, 1u);
                if (idx < CAP) list[idx] = ((unsigned)site << 8) | (unsigned)opL;
            }
        }
    }
}

// ---------------- exact f64 repair, wave-parallel (1 wave per flagged pipeline) ----------
__global__ __launch_bounds__(256) void k_repair(
    const float* __restrict__ x, const float* __restrict__ W,
    const float* __restrict__ gamma, const float* __restrict__ beta,
    const float* __restrict__ rmean, const float* __restrict__ rvar,
    float* __restrict__ out, const unsigned* __restrict__ cnt,
    const unsigned* __restrict__ list)
{
    unsigned count = *cnt;
    if (count > CAP) count = CAP;
    const int lane = threadIdx.x & 63;
    const unsigned gw = (blockIdx.x * 256u + threadIdx.x) >> 6;   // global wave id
    const unsigned nw = (gridDim.x * 256u) >> 6;
    const int d0 = lane * 8;

    for (unsigned j = gw; j < count; j += nw) {
        const unsigned e = list[j];
        const int op = e & 255;
        const int site = e >> 8;
        const int bI = site >> 10, nI = site & 1023;

        double wv[2][8];
        #pragma unroll
        for (int p = 0; p < 2; ++p) {
            const float* Wr = W + (size_t)(2 * op + p) * D_ + d0;
            const float4 a = *(const float4*)(Wr);
            const float4 b = *(const float4*)(Wr + 4);
            wv[p][0] = a.x; wv[p][1] = a.y; wv[p][2] = a.z; wv[p][3] = a.w;
            wv[p][4] = b.x; wv[p][5] = b.y; wv[p][6] = b.z; wv[p][7] = b.w;
        }

        double h[4][2];
        #pragma unroll
        for (int t = 0; t < 4; ++t) {
            const float* xr = x + (((size_t)t * 32 + bI) * 1024 + nI) * D_ + d0;
            const float4 a = *(const float4*)(xr);
            const float4 b = *(const float4*)(xr + 4);
            const double xv[8] = {(double)a.x, (double)a.y, (double)a.z, (double)a.w,
                                  (double)b.x, (double)b.y, (double)b.z, (double)b.w};
            #pragma unroll
            for (int p = 0; p < 2; ++p) {
                double s0 = 0, s1 = 0, s2 = 0, s3 = 0;
                s0 = fma(xv[0], wv[p][0], s0); s1 = fma(xv[1], wv[p][1], s1);
                s2 = fma(xv[2], wv[p][2], s2); s3 = fma(xv[3], wv[p][3], s3);
                s0 = fma(xv[4], wv[p][4], s0); s1 = fma(xv[5], wv[p][5], s1);
                s2 = fma(xv[6], wv[p][6], s2); s3 = fma(xv[7], wv[p][7], s3);
                double s = (s0 + s1) + (s2 + s3);
                #pragma unroll
                for (int off = 32; off > 0; off >>= 1)
                    s += __shfl_xor(s, off, 64);
                h[t][p] = s;
            }
        }

        double iv[2], ad[2];
        #pragma unroll
        for (int p = 0; p < 2; ++p) {
            const int c = 2 * op + p;
            iv[p] = (double)gamma[c] / sqrt((double)rvar[c] + 1e-5);
            ad[p] = (double)beta[c] - (double)rmean[c] * iv[p];
        }
        double v = 0.0;
        #pragma unroll
        for (int t = 0; t < 4; ++t) {
            const double h0 = h[t][0] * iv[0] + ad[0];
            const double h1 = h[t][1] * iv[1] + ad[1];
            const double m = fmax(h0, h1);
            v = (v + m) * 0.5;
            const bool sp = (v >= 1.0);
            if (lane == t)
                out[(((size_t)t * 32 + bI) * 1024 + nI) * 256 + op] = sp ? 1.0f : 0.0f;
            if (sp) v = 0.0;
        }
    }
}

// ---------------- fallback (round-1 exact f64 kernel) ----------------
constexpr int FB_SITES = 32, FB_ROWS = 128, FB_BN = 64, FB_BK = 16;

__global__ __launch_bounds__(256)
void snn_fused_f64(const float* __restrict__ x, const float* __restrict__ W,
                   const float* __restrict__ gamma, const float* __restrict__ beta,
                   const float* __restrict__ rmean, const float* __restrict__ rvar,
                   float* __restrict__ out)
{
    __shared__ float As[FB_BK][FB_ROWS];
    __shared__ float Bs[FB_BK][FB_BN];
    const int tid = threadIdx.x;
    const int tx = tid & 15, ty = tid >> 4;
    const int c0 = blockIdx.x * FB_BN;
    const int site_base = blockIdx.y * FB_SITES;
    const int b = site_base / N_, n0 = site_base % N_;
    const int lrow = tid >> 1, lk = (tid & 1) * 8;
    const int s_l = lrow >> 2, t_l = lrow & 3;
    const float* xrow = x + (size_t)((t_l * B_ + b) * N_ + (n0 + s_l)) * D_ + lk;
    const int wc = tid & 63, wk = (tid >> 6) * 4;
    const float* wrow = W + (size_t)(c0 + wc) * D_ + wk;
    double acc[8][4];
    #pragma unroll
    for (int i = 0; i < 8; ++i)
        #pragma unroll
        for (int j = 0; j < 4; ++j) acc[i][j] = 0.0;
    for (int k0 = 0; k0 < D_; k0 += FB_BK) {
        const float4 a0 = *(const float4*)(xrow + k0);
        const float4 a1 = *(const float4*)(xrow + k0 + 4);
        const float4 w4 = *(const float4*)(wrow + k0);
        As[lk + 0][lrow] = a0.x; As[lk + 1][lrow] = a0.y; As[lk + 2][lrow] = a0.z; As[lk + 3][lrow] = a0.w;
        As[lk + 4][lrow] = a1.x; As[lk + 5][lrow] = a1.y; As[lk + 6][lrow] = a1.z; As[lk + 7][lrow] = a1.w;
        Bs[wk + 0][wc] = w4.x; Bs[wk + 1][wc] = w4.y; Bs[wk + 2][wc] = w4.z; Bs[wk + 3][wc] = w4.w;
        __syncthreads();
        #pragma unroll
        for (int k = 0; k < FB_BK; ++k) {
            const float4 af0 = *(const float4*)&As[k][ty * 8];
            const float4 af1 = *(const float4*)&As[k][ty * 8 + 4];
            const float4 bf = *(const float4*)&Bs[k][tx * 4];
            const double ad[8] = {(double)af0.x, (double)af0.y, (double)af0.z, (double)af0.w,
                                  (double)af1.x, (double)af1.y, (double)af1.z, (double)af1.w};
            const double bd[4] = {(double)bf.x, (double)bf.y, (double)bf.z, (double)bf.w};
            #pragma unroll
            for (int i = 0; i < 8; ++i)
                #pragma unroll
                for (int j = 0; j < 4; ++j) acc[i][j] = fma(ad[i], bd[j], acc[i][j]);
        }
        __syncthreads();
    }
    double invd[4], addd[4];
    #pragma unroll
    for (int j = 0; j < 4; ++j) {
        const int c = c0 + tx * 4 + j;
        const double ivv = (double)gamma[c] / sqrt((double)rvar[c] + 1e-5);
        invd[j] = ivv; addd[j] = (double)beta[c] - (double)rmean[c] * ivv;
    }
    #pragma unroll
    for (int si = 0; si < 2; ++si) {
        const int n = n0 + ty * 2 + si;
        #pragma unroll
        for (int p = 0; p < 2; ++p) {
            const int op = (c0 >> 1) + tx * 2 + p;
            double v = 0.0;
            #pragma unroll
            for (int t = 0; t < 4; ++t) {
                const int i = si * 4 + t;
                const double h0 = acc[i][2 * p] * invd[2 * p] + addd[2 * p];
                const double h1 = acc[i][2 * p + 1] * invd[2 * p + 1] + addd[2 * p + 1];
                const double m = fmax(h0, h1);
                v = v + (m - v) * 0.5;
                const bool sp = (v >= 1.0);
                out[((size_t)(t * B_ + b) * N_ + n) * OP_ + op] = sp ? 1.0f : 0.0f;
                if (sp) v = 0.0;
            }
        }
    }
}

extern "C" void kernel_launch(void* const* d_in, const int* in_sizes, int n_in,
                              void* d_out, int out_size, void* d_ws, size_t ws_size,
                              hipStream_t stream)
{
    const float* x     = (const float*)d_in[0];
    const float* W     = (const float*)d_in[1];
    const float* gamma = (const float*)d_in[2];
    const float* beta  = (const float*)d_in[3];
    const float* rmean = (const float*)d_in[4];
    const float* rvar  = (const float*)d_in[5];
    float* out = (float*)d_out;

    if (ws_size < WS_NEED) {
        dim3 grid(O_ / FB_BN, (B_ * N_) / FB_SITES);
        snn_fused_f64<<<grid, dim3(256), 0, stream>>>(x, W, gamma, beta, rmean, rvar, out);
        return;
    }

    char* ws = (char*)d_ws;
    unsigned* cnt = (unsigned*)(ws + WS_CNT);
    unsigned short* wp = (unsigned short*)(ws + WS_WP);
    unsigned* list = (unsigned*)(ws + WS_LIST);

    k_wprep<<<256, 256, 0, stream>>>(W, wp, cnt);
    k_gemm<<<4096, 256, 2 * BUFSZ, stream>>>(x, wp, gamma, beta, rmean, rvar, out, cnt, list);
    k_repair<<<512, 256, 0, stream>>>(x, W, gamma, beta, rmean, rvar, out, cnt, list);
}

// Round 19
// 175.759 us; speedup vs baseline: 1.4089x; 1.1476x over previous
//
#include <hip/hip_runtime.h>

constexpr int T_ = 4, B_ = 32, N_ = 1024, D_ = 512, O_ = 512, OP_ = 256;
constexpr int M_ = T_ * B_ * N_;
constexpr unsigned CAP = 1u * 1024 * 1024;

// ---- ws layout (bytes) ----
constexpr size_t WS_CNT  = 0;
constexpr size_t WS_WP   = 1u << 20;                  // 512 KiB fragment-ordered W (hi only)
constexpr size_t WS_LIST = WS_WP + (1u << 19);
constexpr size_t WS_NEED = WS_LIST + (size_t)CAP * 4;

constexpr int RSTRIDE = 72;                           // padded LDS row stride (bytes)
constexpr int BUFSZ   = 128 * RSTRIDE;                // 9216 B per buffer

typedef __attribute__((ext_vector_type(8)))  short bf8;
typedef __attribute__((ext_vector_type(16))) float f16v;

union U2B { struct { uint2 a, b; } p; bf8 v; };

__device__ __forceinline__ unsigned cvtpk(float x0, float x1) {
    unsigned r;
    asm("v_cvt_pk_bf16_f32 %0, %1, %2" : "=v"(r) : "v"(x0), "v"(x1));
    return r;
}

// ---------------- W prep: 32x32-fragment-ordered hi split + cnt reset ----------------
// chunk c = [panel:8][j:16][q:4][lane:64], 16B each; q = eo*2 + Kh.
// col = colblk*128 + half*64 + 2*(lane&31) + eo ; k = j*32 + Kh*16 + (lane>>5)*8 .. +8
__global__ __launch_bounds__(256) void k_wprep(const float* __restrict__ W,
                                               unsigned short* __restrict__ wp,
                                               unsigned* __restrict__ cnt)
{
    if (blockIdx.x == 0 && threadIdx.x == 0) *cnt = 0u;
    const int c = blockIdx.x * 256 + threadIdx.x;      // 0..32767
    const int lane = c & 63, q = (c >> 6) & 3, j = (c >> 8) & 15, panel = c >> 12;
    const int colblk = panel >> 1, half = panel & 1;
    const int eo = (q >> 1) & 1, Kh = q & 1;
    const int col = colblk * 128 + half * 64 + 2 * (lane & 31) + eo;
    const int k0 = j * 32 + Kh * 16 + (lane >> 5) * 8;
    const float* src = W + (size_t)col * 512 + k0;
    const float4 v0 = *(const float4*)(src);
    const float4 v1 = *(const float4*)(src + 4);
    const unsigned o0 = cvtpk(v0.x, v0.y), o1 = cvtpk(v0.z, v0.w);
    const unsigned o2 = cvtpk(v1.x, v1.y), o3 = cvtpk(v1.z, v1.w);
    *(uint4*)(wp + (size_t)c * 8) = make_uint4(o0, o1, o2, o3);
}

// -------- 1-term fused GEMM (32x32x16 MFMA, 72B-padded LDS rows) --------
// h ~= xh*wh ; dropped terms sigma(dv) ~= 9e-4 -> flag |v-1|<2.5e-2 (28 sigma)
// and f64-repair flagged pipelines. 4 waves, 128x128 tile, K-step 32,
// LDS 2 x 9216 B (hi only). B halves reissued only after their MFMA cluster
// consumed them (no in-flight register WAR).
__global__ __launch_bounds__(256, 3) void k_gemm(
    const float* __restrict__ x, const unsigned short* __restrict__ wp,
    const float* __restrict__ gamma, const float* __restrict__ beta,
    const float* __restrict__ rmean, const float* __restrict__ rvar,
    float* __restrict__ out, unsigned* __restrict__ cnt, unsigned* __restrict__ list)
{
    extern __shared__ char lds[];
    const int tid  = threadIdx.x;
    const int lane = tid & 63;
    const int wid  = tid >> 6;

    const int dd = blockIdx.x;                  // XCD-aware swizzle
    const int w  = (dd & 7) * 512 + (dd >> 3);
    const int colblk = w & 3, rowblk = w >> 2;
    const int c0  = colblk * 128;
    const int wr0 = (wid >> 1) * 64, wc0 = (wid & 1) * 64;

    // ---- BN constants (per-lane col pair) ----
    const int cE = c0 + wc0 + 2 * (lane & 31);
    const int cO = cE + 1;
    const float invE = gamma[cE] / sqrtf(rvar[cE] + 1e-5f);
    const float addE = beta[cE] - rmean[cE] * invE;
    const float invO = gamma[cO] / sqrtf(rvar[cO] + 1e-5f);
    const float addO = beta[cO] - rmean[cO] * invO;
    asm volatile("s_waitcnt vmcnt(0)" ::: "memory");
    __builtin_amdgcn_sched_barrier(0);

    // ---- A staging map (2 threads/row): arow 0..127, kh = 16-float half ----
    const int arow = tid >> 1;
    const int kh   = tid & 1;
    const int t_a  = arow & 3;
    const int sl_a = arow >> 2;
    const unsigned vA = (unsigned)(t_a * 32768 + rowblk * 32 + sl_a) * 2048u
                      + (unsigned)kh * 64u;
    const int wA0 = arow * RSTRIDE + kh * 32;

    // ---- A-fragment read addrs: frag (rt,Kh): row = wr0+rt*32+(lane&31) ----
    int rA00, rA01, rA10, rA11;
    {
        const int qv = lane & 31, hs = lane >> 5;
        const int r0 = wr0 + qv, r1 = wr0 + 32 + qv;
        rA00 = r0 * RSTRIDE + 0  + hs * 16;
        rA01 = r0 * RSTRIDE + 32 + hs * 16;
        rA10 = r1 * RSTRIDE + 0  + hs * 16;
        rA11 = r1 * RSTRIDE + 32 + hs * 16;
    }

    // ---- B voffset base (fragment-ordered, coalesced): panel stride 64 KiB ----
    const int panel = colblk * 2 + (wid & 1);
    const unsigned vBb = ((unsigned)panel << 16) + (unsigned)lane * 16u;

    f16v accE[2], accO[2];
    #pragma unroll
    for (int i = 0; i < 2; ++i) { accE[i] = (f16v)0.0f; accO[i] = (f16v)0.0f; }

    float4 Aa[4], Ab[4];
    bf8 Bf[4];          // [eo*2 + Kh]
    bf8 ah[4];          // [rt*2 + Kh]

#define SCHED __builtin_amdgcn_sched_barrier(0)

#define ALOAD(AI, K)                                                              \
    do {                                                                          \
        asm volatile("global_load_dwordx4 %0, %1, %2 offset:%3"                   \
                     : "=v"(AI[0]) : "v"(vA), "s"(x), "n"((K)*128 + 0)  : "memory"); \
        asm volatile("global_load_dwordx4 %0, %1, %2 offset:%3"                   \
                     : "=v"(AI[1]) : "v"(vA), "s"(x), "n"((K)*128 + 16) : "memory"); \
        asm volatile("global_load_dwordx4 %0, %1, %2 offset:%3"                   \
                     : "=v"(AI[2]) : "v"(vA), "s"(x), "n"((K)*128 + 32) : "memory"); \
        asm volatile("global_load_dwordx4 %0, %1, %2 offset:%3"                   \
                     : "=v"(AI[3]) : "v"(vA), "s"(x), "n"((K)*128 + 48) : "memory"); \
    } while (0)

// load the 2 B frags of K-half KH (both eo) for step K
#define BGRPH(KH, K)                                                              \
    do {                                                                          \
        const unsigned vk = vBb + (unsigned)(K) * 4096u;                          \
        asm volatile("global_load_dwordx4 %0, %1, %2 offset:%3"                   \
                     : "=v"(Bf[0 + (KH)]) : "v"(vk), "s"(wp),                     \
                       "n"((KH)*1024)        : "memory");                         \
        asm volatile("global_load_dwordx4 %0, %1, %2 offset:%3"                   \
                     : "=v"(Bf[2 + (KH)]) : "v"(vk), "s"(wp),                     \
                       "n"(2048 + (KH)*1024) : "memory");                         \
    } while (0)

// read one A hi-fragment ah[IDX] from buf (J&1) at addr RA (2x b64 at +0/+8)
#define DSR1(J, IDX, RA)                                                          \
    do {                                                                          \
        const char* bR = lds + ((J) & 1) * BUFSZ;                                 \
        U2B t;                                                                    \
        t.p.a = *(const uint2*)(bR + (RA));                                       \
        t.p.b = *(const uint2*)(bR + (RA) + 8);                                   \
        ah[IDX] = t.v;                                                            \
    } while (0)

// hi -> 4 consecutive 8B slots of this thread's 32B half-row
#define CONVW(AC, BUF)                                                            \
    do {                                                                          \
        char* pw = lds + (BUF) * BUFSZ + wA0;                                     \
        const unsigned q0 = cvtpk(AC[0].x, AC[0].y), q1 = cvtpk(AC[0].z, AC[0].w);\
        const unsigned q2 = cvtpk(AC[1].x, AC[1].y), q3 = cvtpk(AC[1].z, AC[1].w);\
        *(uint2*)(pw + 0)  = make_uint2(q0, q1);                                  \
        *(uint2*)(pw + 8)  = make_uint2(q2, q3);                                  \
        const unsigned q4 = cvtpk(AC[2].x, AC[2].y), q5 = cvtpk(AC[2].z, AC[2].w);\
        const unsigned q6 = cvtpk(AC[3].x, AC[3].y), q7 = cvtpk(AC[3].z, AC[3].w);\
        *(uint2*)(pw + 16) = make_uint2(q4, q5);                                  \
        *(uint2*)(pw + 24) = make_uint2(q6, q7);                                  \
    } while (0)

// 4 MFMAs (32x32x16) for K-half KH: both row-tiles x both eo
#define MGRP(KH)                                                                  \
    do {                                                                          \
        accE[0] = __builtin_amdgcn_mfma_f32_32x32x16_bf16(ah[0 + (KH)], Bf[0 + (KH)], accE[0], 0, 0, 0); \
        accO[0] = __builtin_amdgcn_mfma_f32_32x32x16_bf16(ah[0 + (KH)], Bf[2 + (KH)], accO[0], 0, 0, 0); \
        accE[1] = __builtin_amdgcn_mfma_f32_32x32x16_bf16(ah[2 + (KH)], Bf[0 + (KH)], accE[1], 0, 0, 0); \
        accO[1] = __builtin_amdgcn_mfma_f32_32x32x16_bf16(ah[2 + (KH)], Bf[2 + (KH)], accO[1], 0, 0, 0); \
    } while (0)

#define PRIO1 __builtin_amdgcn_s_setprio(1)
#define PRIO0 __builtin_amdgcn_s_setprio(0)

// Ledger at ITER(J) top: outstanding (oldest first) = {A(J+1):4, B0(J):2, B1(J):2}.
// vmcnt(4) retires A(J+1). After ALOAD(J+2): {B0,B1,A(J+2)} = 8; vmcnt(NB0)
// retires B0(J). MGRP(0) consumes B0 -> BGRPH(0,J+1). vmcnt(NB1) retires B1(J).
// MGRP(1) consumes B1 -> CONVW -> BGRPH(1,J+1). J<=13: NB0=NB1=6; J=14: 2/2.
#define ITER(J, ATGT, ACV, NB0, NB1)                                              \
    do {                                                                          \
        SCHED;                                                                    \
        asm volatile("s_waitcnt vmcnt(4)" ::: "memory");     /* A(J+1) ready */   \
        asm volatile("s_waitcnt lgkmcnt(0)" ::: "memory");   /* drain own ds */   \
        __builtin_amdgcn_s_barrier();                                             \
        SCHED;                                                                    \
        DSR1(J, 0, rA00);                                                         \
        DSR1(J, 1, rA01);                                                         \
        DSR1(J, 2, rA10);                                                         \
        DSR1(J, 3, rA11);                                                         \
        SCHED;                                                                    \
        if ((J) + 2 <= 15) { ALOAD(ATGT, (J) + 2); }                              \
        SCHED;                                                                    \
        asm volatile("s_waitcnt vmcnt(" NB0 ")" ::: "memory"); /* B0(J) ready */  \
        asm volatile("s_waitcnt lgkmcnt(0)" ::: "memory");     /* ds reads done */\
        SCHED;                                                                    \
        PRIO1; MGRP(0); PRIO0;                                                    \
        SCHED;                                                                    \
        BGRPH(0, (J) + 1);                                                        \
        SCHED;                                                                    \
        asm volatile("s_waitcnt vmcnt(" NB1 ")" ::: "memory"); /* B1(J) ready */  \
        SCHED;                                                                    \
        PRIO1; MGRP(1); PRIO0;                                                    \
        SCHED;                                                                    \
        CONVW(ACV, ((J) + 1) & 1);                             /* off crit path */\
        SCHED;                                                                    \
        BGRPH(1, (J) + 1);                                                        \
        SCHED;                                                                    \
    } while (0)

    // ---- prologue: A(0),A(1),B(0); retire A0; conv A0 -> buf0 ----
    SCHED;
    ALOAD(Aa, 0);
    ALOAD(Ab, 1);
    SCHED;
    BGRPH(0, 0);
    BGRPH(1, 0);
    SCHED;
    asm volatile("s_waitcnt vmcnt(8)" ::: "memory");   // retire A(0)
    SCHED;
    CONVW(Aa, 0);
    SCHED;

    ITER(0,  Aa, Ab, "6", "6");
    ITER(1,  Ab, Aa, "6", "6");
    ITER(2,  Aa, Ab, "6", "6");
    ITER(3,  Ab, Aa, "6", "6");
    ITER(4,  Aa, Ab, "6", "6");
    ITER(5,  Ab, Aa, "6", "6");
    ITER(6,  Aa, Ab, "6", "6");
    ITER(7,  Ab, Aa, "6", "6");
    ITER(8,  Aa, Ab, "6", "6");
    ITER(9,  Ab, Aa, "6", "6");
    ITER(10, Aa, Ab, "6", "6");
    ITER(11, Ab, Aa, "6", "6");
    ITER(12, Aa, Ab, "6", "6");
    ITER(13, Ab, Aa, "6", "6");
    ITER(14, Aa, Ab, "2", "2");

    // ---- J = 15: tail; outstanding = {B0(15):2, B1(15):2} ----
    SCHED;
    asm volatile("s_waitcnt lgkmcnt(0)" ::: "memory");
    __builtin_amdgcn_s_barrier();
    SCHED;
    DSR1(15, 0, rA00);
    DSR1(15, 1, rA01);
    DSR1(15, 2, rA10);
    DSR1(15, 3, rA11);
    SCHED;
    asm volatile("s_waitcnt vmcnt(2)" ::: "memory");    // B0(15) ready
    asm volatile("s_waitcnt lgkmcnt(0)" ::: "memory");
    SCHED;
    PRIO1; MGRP(0); PRIO0;
    SCHED;
    asm volatile("s_waitcnt vmcnt(0)" ::: "memory");    // B1(15) ready
    SCHED;
    PRIO1; MGRP(1); PRIO0;
    SCHED;

#undef ITER
#undef PRIO1
#undef PRIO0
#undef MGRP
#undef DSR1
#undef CONVW
#undef BGRPH
#undef ALOAD
#undef SCHED

    // ---- epilogue: BN -> pool -> LIF, flag near-threshold pipelines (28-sigma) ----
    // C layout (32x32): col = lane&31 (E even / O odd), row = (reg&3) + 8*(reg>>2) + 4*(lane>>5).
    const int opL = ((c0 + wc0) >> 1) + (lane & 31);
    #pragma unroll
    for (int rt = 0; rt < 2; ++rt) {
        #pragma unroll
        for (int g = 0; g < 4; ++g) {
            const int site = rowblk * 32 + (wid >> 1) * 16 + rt * 8 + 2 * g + (lane >> 5);
            const int bI = site >> 10, nI = site & 1023;
            float v = 0.0f;
            bool flg = false;
            #pragma unroll
            for (int t = 0; t < 4; ++t) {
                const float hE = accE[rt][g * 4 + t] * invE + addE;
                const float hO = accO[rt][g * 4 + t] * invO + addO;
                const float m = fmaxf(hE, hO);
                v = (v + m) * 0.5f;
                const float dv = v - 1.0f;
                const bool sp = dv >= 0.0f;
                out[(((size_t)t * 32 + bI) * 1024 + nI) * 256 + opL] = sp ? 1.0f : 0.0f;
                flg |= (fabsf(dv) < 2.5e-2f);
                if (sp) v = 0.0f;
            }
            if (flg) {
                unsigned idx = atomicAdd(cnt, 1u);
                if (idx < CAP) list[idx] = ((unsigned)site << 8) | (unsigned)opL;
            }
        }
    }
}

// ---------------- exact f64 repair, wave-parallel (1 wave per flagged pipeline) ----------
__global__ __launch_bounds__(256) void k_repair(
    const float* __restrict__ x, const float* __restrict__ W,
    const float* __restrict__ gamma, const float* __restrict__ beta,
    const float* __restrict__ rmean, const float* __restrict__ rvar,
    float* __restrict__ out, const unsigned* __restrict__ cnt,
    const unsigned* __restrict__ list)
{
    unsigned count = *cnt;
    if (count > CAP) count = CAP;
    const int lane = threadIdx.x & 63;
    const unsigned gw = (blockIdx.x * 256u + threadIdx.x) >> 6;   // global wave id
    const unsigned nw = (gridDim.x * 256u) >> 6;
    const int d0 = lane * 8;

    for (unsigned j = gw; j < count; j += nw) {
        const unsigned e = list[j];
        const int op = e & 255;
        const int site = e >> 8;
        const int bI = site >> 10, nI = site & 1023;

        double wv[2][8];
        #pragma unroll
        for (int p = 0; p < 2; ++p) {
            const float* Wr = W + (size_t)(2 * op + p) * D_ + d0;
            const float4 a = *(const float4*)(Wr);
            const float4 b = *(const float4*)(Wr + 4);
            wv[p][0] = a.x; wv[p][1] = a.y; wv[p][2] = a.z; wv[p][3] = a.w;
            wv[p][4] = b.x; wv[p][5] = b.y; wv[p][6] = b.z; wv[p][7] = b.w;
        }

        double h[4][2];
        #pragma unroll
        for (int t = 0; t < 4; ++t) {
            const float* xr = x + (((size_t)t * 32 + bI) * 1024 + nI) * D_ + d0;
            const float4 a = *(const float4*)(xr);
            const float4 b = *(const float4*)(xr + 4);
            const double xv[8] = {(double)a.x, (double)a.y, (double)a.z, (double)a.w,
                                  (double)b.x, (double)b.y, (double)b.z, (double)b.w};
            #pragma unroll
            for (int p = 0; p < 2; ++p) {
                double s0 = 0, s1 = 0, s2 = 0, s3 = 0;
                s0 = fma(xv[0], wv[p][0], s0); s1 = fma(xv[1], wv[p][1], s1);
                s2 = fma(xv[2], wv[p][2], s2); s3 = fma(xv[3], wv[p][3], s3);
                s0 = fma(xv[4], wv[p][4], s0); s1 = fma(xv[5], wv[p][5], s1);
                s2 = fma(xv[6], wv[p][6], s2); s3 = fma(xv[7], wv[p][7], s3);
                double s = (s0 + s1) + (s2 + s3);
                #pragma unroll
                for (int off = 32; off > 0; off >>= 1)
                    s += __shfl_xor(s, off, 64);
                h[t][p] = s;
            }
        }

        double iv[2], ad[2];
        #pragma unroll
        for (int p = 0; p < 2; ++p) {
            const int c = 2 * op + p;
            iv[p] = (double)gamma[c] / sqrt((double)rvar[c] + 1e-5);
            ad[p] = (double)beta[c] - (double)rmean[c] * iv[p];
        }
        double v = 0.0;
        #pragma unroll
        for (int t = 0; t < 4; ++t) {
            const double h0 = h[t][0] * iv[0] + ad[0];
            const double h1 = h[t][1] * iv[1] + ad[1];
            const double m = fmax(h0, h1);
            v = (v + m) * 0.5;
            const bool sp = (v >= 1.0);
            if (lane == t)
                out[(((size_t)t * 32 + bI) * 1024 + nI) * 256 + op] = sp ? 1.0f : 0.0f;
            if (sp) v = 0.0;
        }
    }
}

// ---------------- fallback (round-1 exact f64 kernel) ----------------
constexpr int FB_SITES = 32, FB_ROWS = 128, FB_BN = 64, FB_BK = 16;

__global__ __launch_bounds__(256)
void snn_fused_f64(const float* __restrict__ x, const float* __restrict__ W,
                   const float* __restrict__ gamma, const float* __restrict__ beta,
                   const float* __restrict__ rmean, const float* __restrict__ rvar,
                   float* __restrict__ out)
{
    __shared__ float As[FB_BK][FB_ROWS];
    __shared__ float Bs[FB_BK][FB_BN];
    const int tid = threadIdx.x;
    const int tx = tid & 15, ty = tid >> 4;
    const int c0 = blockIdx.x * FB_BN;
    const int site_base = blockIdx.y * FB_SITES;
    const int b = site_base / N_, n0 = site_base % N_;
    const int lrow = tid >> 1, lk = (tid & 1) * 8;
    const int s_l = lrow >> 2, t_l = lrow & 3;
    const float* xrow = x + (size_t)((t_l * B_ + b) * N_ + (n0 + s_l)) * D_ + lk;
    const int wc = tid & 63, wk = (tid >> 6) * 4;
    const float* wrow = W + (size_t)(c0 + wc) * D_ + wk;
    double acc[8][4];
    #pragma unroll
    for (int i = 0; i < 8; ++i)
        #pragma unroll
        for (int j = 0; j < 4; ++j) acc[i][j] = 0.0;
    for (int k0 = 0; k0 < D_; k0 += FB_BK) {
        const float4 a0 = *(const float4*)(xrow + k0);
        const float4 a1 = *(const float4*)(xrow + k0 + 4);
        const float4 w4 = *(const float4*)(wrow + k0);
        As[lk + 0][lrow] = a0.x; As[lk + 1][lrow] = a0.y; As[lk + 2][lrow] = a0.z; As[lk + 3][lrow] = a0.w;
        As[lk + 4][lrow] = a1.x; As[lk + 5][lrow] = a1.y; As[lk + 6][lrow] = a1.z; As[lk + 7][lrow] = a1.w;
        Bs[wk + 0][wc] = w4.x; Bs[wk + 1][wc] = w4.y; Bs[wk + 2][wc] = w4.z; Bs[wk + 3][wc] = w4.w;
        __syncthreads();
        #pragma unroll
        for (int k = 0; k < FB_BK; ++k) {
            const float4 af0 = *(const float4*)&As[k][ty * 8];
            const float4 af1 = *(const float4*)&As[k][ty * 8 + 4];
            const float4 bf = *(const float4*)&Bs[k][tx * 4];
            const double ad[8] = {(double)af0.x, (double)af0.y, (double)af0.z, (double)af0.w,
                                  (double)af1.x, (double)af1.y, (double)af1.z, (double)af1.w};
            const double bd[4] = {(double)bf.x, (double)bf.y, (double)bf.z, (double)bf.w};
            #pragma unroll
            for (int i = 0; i < 8; ++i)
                #pragma unroll
                for (int j = 0; j < 4; ++j) acc[i][j] = fma(ad[i], bd[j], acc[i][j]);
        }
        __syncthreads();
    }
    double invd[4], addd[4];
    #pragma unroll
    for (int j = 0; j < 4; ++j) {
        const int c = c0 + tx * 4 + j;
        const double ivv = (double)gamma[c] / sqrt((double)rvar[c] + 1e-5);
        invd[j] = ivv; addd[j] = (double)beta[c] - (double)rmean[c] * ivv;
    }
    #pragma unroll
    for (int si = 0; si < 2; ++si) {
        const int n = n0 + ty * 2 + si;
        #pragma unroll
        for (int p = 0; p < 2; ++p) {
            const int op = (c0 >> 1) + tx * 2 + p;
            double v = 0.0;
            #pragma unroll
            for (int t = 0; t < 4; ++t) {
                const int i = si * 4 + t;
                const double h0 = acc[i][2 * p] * invd[2 * p] + addd[2 * p];
                const double h1 = acc[i][2 * p + 1] * invd[2 * p + 1] + addd[2 * p + 1];
                const double m = fmax(h0, h1);
                v = v + (m - v) * 0.5;
                const bool sp = (v >= 1.0);
                out[((size_t)(t * B_ + b) * N_ + n) * OP_ + op] = sp ? 1.0f : 0.0f;
                if (sp) v = 0.0;
            }
        }
    }
}

extern "C" void kernel_launch(void* const* d_in, const int* in_sizes, int n_in,
                              void* d_out, int out_size, void* d_ws, size_t ws_size,
                              hipStream_t stream)
{
    const float* x     = (const float*)d_in[0];
    const float* W     = (const float*)d_in[1];
    const float* gamma = (const float*)d_in[2];
    const float* beta  = (const float*)d_in[3];
    const float* rmean = (const float*)d_in[4];
    const float* rvar  = (const float*)d_in[5];
    float* out = (float*)d_out;

    if (ws_size < WS_NEED) {
        dim3 grid(O_ / FB_BN, (B_ * N_) / FB_SITES);
        snn_fused_f64<<<grid, dim3(256), 0, stream>>>(x, W, gamma, beta, rmean, rvar, out);
        return;
    }

    char* ws = (char*)d_ws;
    unsigned* cnt = (unsigned*)(ws + WS_CNT);
    unsigned short* wp = (unsigned short*)(ws + WS_WP);
    unsigned* list = (unsigned*)(ws + WS_LIST);

    k_wprep<<<128, 256, 0, stream>>>(W, wp, cnt);
    k_gemm<<<4096, 256, 2 * BUFSZ, stream>>>(x, wp, gamma, beta, rmean, rvar, out, cnt, list);
    k_repair<<<512, 256, 0, stream>>>(x, W, gamma, beta, rmean, rvar, out, cnt, list);
}

// Round 22
// 175.669 us; speedup vs baseline: 1.4096x; 1.0005x over previous
//
#include <hip/hip_runtime.h>

constexpr int T_ = 4, B_ = 32, N_ = 1024, D_ = 512, O_ = 512, OP_ = 256;
constexpr int M_ = T_ * B_ * N_;
constexpr unsigned CAP = 1u * 1024 * 1024;

// ---- ws layout (bytes) ----
constexpr size_t WS_CNT  = 0;
constexpr size_t WS_WP   = 1u << 20;                  // 512 KiB fragment-ordered W (hi only)
constexpr size_t WS_LIST = WS_WP + (1u << 19);
constexpr size_t WS_NEED = WS_LIST + (size_t)CAP * 4;

constexpr int RSTRIDE = 72;                           // padded LDS row stride (bytes)
constexpr int BUFSZ   = 128 * RSTRIDE;                // 9216 B per buffer

typedef __attribute__((ext_vector_type(8)))  short bf8;
typedef __attribute__((ext_vector_type(16))) float f16v;

union U2B { struct { uint2 a, b; } p; bf8 v; };

__device__ __forceinline__ unsigned cvtpk(float x0, float x1) {
    unsigned r;
    asm("v_cvt_pk_bf16_f32 %0, %1, %2" : "=v"(r) : "v"(x0), "v"(x1));
    return r;
}

// ---------------- W prep: 32x32-fragment-ordered hi split + cnt reset ----------------
// chunk c = [panel:8][j:16][q:4][lane:64], 16B each; q = eo*2 + Kh.
// col = colblk*128 + half*64 + 2*(lane&31) + eo ; k = j*32 + Kh*16 + (lane>>5)*8 .. +8
__global__ __launch_bounds__(256) void k_wprep(const float* __restrict__ W,
                                               unsigned short* __restrict__ wp,
                                               unsigned* __restrict__ cnt)
{
    if (blockIdx.x == 0 && threadIdx.x == 0) *cnt = 0u;
    const int c = blockIdx.x * 256 + threadIdx.x;      // 0..32767
    const int lane = c & 63, q = (c >> 6) & 3, j = (c >> 8) & 15, panel = c >> 12;
    const int colblk = panel >> 1, half = panel & 1;
    const int eo = (q >> 1) & 1, Kh = q & 1;
    const int col = colblk * 128 + half * 64 + 2 * (lane & 31) + eo;
    const int k0 = j * 32 + Kh * 16 + (lane >> 5) * 8;
    const float* src = W + (size_t)col * 512 + k0;
    const float4 v0 = *(const float4*)(src);
    const float4 v1 = *(const float4*)(src + 4);
    const unsigned o0 = cvtpk(v0.x, v0.y), o1 = cvtpk(v0.z, v0.w);
    const unsigned o2 = cvtpk(v1.x, v1.y), o3 = cvtpk(v1.z, v1.w);
    *(uint4*)(wp + (size_t)c * 8) = make_uint4(o0, o1, o2, o3);
}

// -------- 1-term fused GEMM (32x32x16 MFMA, 72B-padded LDS rows) --------
// h ~= xh*wh ; dropped terms sigma(dv) ~= 9e-4 -> flag |v-1|<2.5e-2 (28 sigma)
// and f64-repair flagged pipelines. 4 waves, 128x128 tile, K-step 32,
// LDS 2 x 9216 B (hi only). B halves reissued only after their MFMA cluster
// consumed them (no in-flight register WAR).
__global__ __launch_bounds__(256, 3) void k_gemm(
    const float* __restrict__ x, const unsigned short* __restrict__ wp,
    const float* __restrict__ gamma, const float* __restrict__ beta,
    const float* __restrict__ rmean, const float* __restrict__ rvar,
    float* __restrict__ out, unsigned* __restrict__ cnt, unsigned* __restrict__ list)
{
    extern __shared__ char lds[];
    const int tid  = threadIdx.x;
    const int lane = tid & 63;
    const int wid  = tid >> 6;

    const int dd = blockIdx.x;                  // XCD-aware swizzle
    const int w  = (dd & 7) * 512 + (dd >> 3);
    const int colblk = w & 3, rowblk = w >> 2;
    const int c0  = colblk * 128;
    const int wr0 = (wid >> 1) * 64, wc0 = (wid & 1) * 64;

    // ---- BN constants (per-lane col pair) ----
    const int cE = c0 + wc0 + 2 * (lane & 31);
    const int cO = cE + 1;
    const float invE = gamma[cE] / sqrtf(rvar[cE] + 1e-5f);
    const float addE = beta[cE] - rmean[cE] * invE;
    const float invO = gamma[cO] / sqrtf(rvar[cO] + 1e-5f);
    const float addO = beta[cO] - rmean[cO] * invO;
    asm volatile("s_waitcnt vmcnt(0)" ::: "memory");
    __builtin_amdgcn_sched_barrier(0);

    // ---- A staging map (2 threads/row): arow 0..127, kh = 16-float half ----
    const int arow = tid >> 1;
    const int kh   = tid & 1;
    const int t_a  = arow & 3;
    const int sl_a = arow >> 2;
    const unsigned vA = (unsigned)(t_a * 32768 + rowblk * 32 + sl_a) * 2048u
                      + (unsigned)kh * 64u;
    const int wA0 = arow * RSTRIDE + kh * 32;

    // ---- A-fragment read addrs: frag (rt,Kh): row = wr0+rt*32+(lane&31) ----
    int rA00, rA01, rA10, rA11;
    {
        const int qv = lane & 31, hs = lane >> 5;
        const int r0 = wr0 + qv, r1 = wr0 + 32 + qv;
        rA00 = r0 * RSTRIDE + 0  + hs * 16;
        rA01 = r0 * RSTRIDE + 32 + hs * 16;
        rA10 = r1 * RSTRIDE + 0  + hs * 16;
        rA11 = r1 * RSTRIDE + 32 + hs * 16;
    }

    // ---- B voffset base (fragment-ordered, coalesced): panel stride 64 KiB ----
    const int panel = colblk * 2 + (wid & 1);
    const unsigned vBb = ((unsigned)panel << 16) + (unsigned)lane * 16u;

    f16v accE[2], accO[2];
    #pragma unroll
    for (int i = 0; i < 2; ++i) { accE[i] = (f16v)0.0f; accO[i] = (f16v)0.0f; }

    float4 Aa[4], Ab[4];
    bf8 Bf[4];          // [eo*2 + Kh]
    bf8 ah[4];          // [rt*2 + Kh]

#define SCHED __builtin_amdgcn_sched_barrier(0)

#define ALOAD(AI, K)                                                              \
    do {                                                                          \
        asm volatile("global_load_dwordx4 %0, %1, %2 offset:%3"                   \
                     : "=v"(AI[0]) : "v"(vA), "s"(x), "n"((K)*128 + 0)  : "memory"); \
        asm volatile("global_load_dwordx4 %0, %1, %2 offset:%3"                   \
                     : "=v"(AI[1]) : "v"(vA), "s"(x), "n"((K)*128 + 16) : "memory"); \
        asm volatile("global_load_dwordx4 %0, %1, %2 offset:%3"                   \
                     : "=v"(AI[2]) : "v"(vA), "s"(x), "n"((K)*128 + 32) : "memory"); \
        asm volatile("global_load_dwordx4 %0, %1, %2 offset:%3"                   \
                     : "=v"(AI[3]) : "v"(vA), "s"(x), "n"((K)*128 + 48) : "memory"); \
    } while (0)

// load the 2 B frags of K-half KH (both eo) for step K
#define BGRPH(KH, K)                                                              \
    do {                                                                          \
        const unsigned vk = vBb + (unsigned)(K) * 4096u;                          \
        asm volatile("global_load_dwordx4 %0, %1, %2 offset:%3"                   \
                     : "=v"(Bf[0 + (KH)]) : "v"(vk), "s"(wp),                     \
                       "n"((KH)*1024)        : "memory");                         \
        asm volatile("global_load_dwordx4 %0, %1, %2 offset:%3"                   \
                     : "=v"(Bf[2 + (KH)]) : "v"(vk), "s"(wp),                     \
                       "n"(2048 + (KH)*1024) : "memory");                         \
    } while (0)

// read one A hi-fragment ah[IDX] from buf (J&1) at addr RA (2x b64 at +0/+8)
#define DSR1(J, IDX, RA)                                                          \
    do {                                                                          \
        const char* bR = lds + ((J) & 1) * BUFSZ;                                 \
        U2B t;                                                                    \
        t.p.a = *(const uint2*)(bR + (RA));                                       \
        t.p.b = *(const uint2*)(bR + (RA) + 8);                                   \
        ah[IDX] = t.v;                                                            \
    } while (0)

// hi -> 4 consecutive 8B slots of this thread's 32B half-row
#define CONVW(AC, BUF)                                                            \
    do {                                                                          \
        char* pw = lds + (BUF) * BUFSZ + wA0;                                     \
        const unsigned q0 = cvtpk(AC[0].x, AC[0].y), q1 = cvtpk(AC[0].z, AC[0].w);\
        const unsigned q2 = cvtpk(AC[1].x, AC[1].y), q3 = cvtpk(AC[1].z, AC[1].w);\
        *(uint2*)(pw + 0)  = make_uint2(q0, q1);                                  \
        *(uint2*)(pw + 8)  = make_uint2(q2, q3);                                  \
        const unsigned q4 = cvtpk(AC[2].x, AC[2].y), q5 = cvtpk(AC[2].z, AC[2].w);\
        const unsigned q6 = cvtpk(AC[3].x, AC[3].y), q7 = cvtpk(AC[3].z, AC[3].w);\
        *(uint2*)(pw + 16) = make_uint2(q4, q5);                                  \
        *(uint2*)(pw + 24) = make_uint2(q6, q7);                                  \
    } while (0)

// 4 MFMAs (32x32x16) for K-half KH: both row-tiles x both eo
#define MGRP(KH)                                                                  \
    do {                                                                          \
        accE[0] = __builtin_amdgcn_mfma_f32_32x32x16_bf16(ah[0 + (KH)], Bf[0 + (KH)], accE[0], 0, 0, 0); \
        accO[0] = __builtin_amdgcn_mfma_f32_32x32x16_bf16(ah[0 + (KH)], Bf[2 + (KH)], accO[0], 0, 0, 0); \
        accE[1] = __builtin_amdgcn_mfma_f32_32x32x16_bf16(ah[2 + (KH)], Bf[0 + (KH)], accE[1], 0, 0, 0); \
        accO[1] = __builtin_amdgcn_mfma_f32_32x32x16_bf16(ah[2 + (KH)], Bf[2 + (KH)], accO[1], 0, 0, 0); \
    } while (0)

#define PRIO1 __builtin_amdgcn_s_setprio(1)
#define PRIO0 __builtin_amdgcn_s_setprio(0)

// Ledger at ITER(J) top: outstanding (oldest first) = {A(J+1):4, B0(J):2, B1(J):2}.
// vmcnt(4) retires A(J+1). After ALOAD(J+2): {B0,B1,A(J+2)} = 8; vmcnt(NB0)
// retires B0(J). MGRP(0) consumes B0 -> BGRPH(0,J+1). vmcnt(NB1) retires B1(J).
// MGRP(1) consumes B1 -> CONVW -> BGRPH(1,J+1). J<=13: NB0=NB1=6; J=14: 2/2.
#define ITER(J, ATGT, ACV, NB0, NB1)                                              \
    do {                                                                          \
        SCHED;                                                                    \
        asm volatile("s_waitcnt vmcnt(4)" ::: "memory");     /* A(J+1) ready */   \
        asm volatile("s_waitcnt lgkmcnt(0)" ::: "memory");   /* drain own ds */   \
        __builtin_amdgcn_s_barrier();                                             \
        SCHED;                                                                    \
        DSR1(J, 0, rA00);                                                         \
        DSR1(J, 1, rA01);                                                         \
        DSR1(J, 2, rA10);                                                         \
        DSR1(J, 3, rA11);                                                         \
        SCHED;                                                                    \
        if ((J) + 2 <= 15) { ALOAD(ATGT, (J) + 2); }                              \
        SCHED;                                                                    \
        asm volatile("s_waitcnt vmcnt(" NB0 ")" ::: "memory"); /* B0(J) ready */  \
        asm volatile("s_waitcnt lgkmcnt(0)" ::: "memory");     /* ds reads done */\
        SCHED;                                                                    \
        PRIO1; MGRP(0); PRIO0;                                                    \
        SCHED;                                                                    \
        BGRPH(0, (J) + 1);                                                        \
        SCHED;                                                                    \
        asm volatile("s_waitcnt vmcnt(" NB1 ")" ::: "memory"); /* B1(J) ready */  \
        SCHED;                                                                    \
        PRIO1; MGRP(1); PRIO0;                                                    \
        SCHED;                                                                    \
        CONVW(ACV, ((J) + 1) & 1);                             /* off crit path */\
        SCHED;                                                                    \
        BGRPH(1, (J) + 1);                                                        \
        SCHED;                                                                    \
    } while (0)

    // ---- prologue: A(0),A(1),B(0); retire A0; conv A0 -> buf0 ----
    SCHED;
    ALOAD(Aa, 0);
    ALOAD(Ab, 1);
    SCHED;
    BGRPH(0, 0);
    BGRPH(1, 0);
    SCHED;
    asm volatile("s_waitcnt vmcnt(8)" ::: "memory");   // retire A(0)
    SCHED;
    CONVW(Aa, 0);
    SCHED;

    ITER(0,  Aa, Ab, "6", "6");
    ITER(1,  Ab, Aa, "6", "6");
    ITER(2,  Aa, Ab, "6", "6");
    ITER(3,  Ab, Aa, "6", "6");
    ITER(4,  Aa, Ab, "6", "6");
    ITER(5,  Ab, Aa, "6", "6");
    ITER(6,  Aa, Ab, "6", "6");
    ITER(7,  Ab, Aa, "6", "6");
    ITER(8,  Aa, Ab, "6", "6");
    ITER(9,  Ab, Aa, "6", "6");
    ITER(10, Aa, Ab, "6", "6");
    ITER(11, Ab, Aa, "6", "6");
    ITER(12, Aa, Ab, "6", "6");
    ITER(13, Ab, Aa, "6", "6");
    ITER(14, Aa, Ab, "2", "2");

    // ---- J = 15: tail; outstanding = {B0(15):2, B1(15):2} ----
    SCHED;
    asm volatile("s_waitcnt lgkmcnt(0)" ::: "memory");
    __builtin_amdgcn_s_barrier();
    SCHED;
    DSR1(15, 0, rA00);
    DSR1(15, 1, rA01);
    DSR1(15, 2, rA10);
    DSR1(15, 3, rA11);
    SCHED;
    asm volatile("s_waitcnt vmcnt(2)" ::: "memory");    // B0(15) ready
    asm volatile("s_waitcnt lgkmcnt(0)" ::: "memory");
    SCHED;
    PRIO1; MGRP(0); PRIO0;
    SCHED;
    asm volatile("s_waitcnt vmcnt(0)" ::: "memory");    // B1(15) ready
    SCHED;
    PRIO1; MGRP(1); PRIO0;
    SCHED;

#undef ITER
#undef PRIO1
#undef PRIO0
#undef MGRP
#undef DSR1
#undef CONVW
#undef BGRPH
#undef ALOAD
#undef SCHED

    // ---- epilogue: BN -> pool -> LIF, flag near-threshold pipelines (28-sigma) ----
    // C layout (32x32): col = lane&31 (E even / O odd), row = (reg&3) + 8*(reg>>2) + 4*(lane>>5).
    const int opL = ((c0 + wc0) >> 1) + (lane & 31);
    #pragma unroll
    for (int rt = 0; rt < 2; ++rt) {
        #pragma unroll
        for (int g = 0; g < 4; ++g) {
            const int site = rowblk * 32 + (wid >> 1) * 16 + rt * 8 + 2 * g + (lane >> 5);
            const int bI = site >> 10, nI = site & 1023;
            float v = 0.0f;
            bool flg = false;
            #pragma unroll
            for (int t = 0; t < 4; ++t) {
                const float hE = accE[rt][g * 4 + t] * invE + addE;
                const float hO = accO[rt][g * 4 + t] * invO + addO;
                const float m = fmaxf(hE, hO);
                v = (v + m) * 0.5f;
                const float dv = v - 1.0f;
                const bool sp = dv >= 0.0f;
                out[(((size_t)t * 32 + bI) * 1024 + nI) * 256 + opL] = sp ? 1.0f : 0.0f;
                flg |= (fabsf(dv) < 2.5e-2f);
                if (sp) v = 0.0f;
            }
            if (flg) {
                unsigned idx = atomicAdd(cnt, 1u);
                if (idx < CAP) list[idx] = ((unsigned)site << 8) | (unsigned)opL;
            }
        }
    }
}

// ---------------- exact f64 repair, wave-parallel (1 wave per flagged pipeline) ----------
__global__ __launch_bounds__(256) void k_repair(
    const float* __restrict__ x, const float* __restrict__ W,
    const float* __restrict__ gamma, const float* __restrict__ beta,
    const float* __restrict__ rmean, const float* __restrict__ rvar,
    float* __restrict__ out, const unsigned* __restrict__ cnt,
    const unsigned* __restrict__ list)
{
    unsigned count = *cnt;
    if (count > CAP) count = CAP;
    const int lane = threadIdx.x & 63;
    const unsigned gw = (blockIdx.x * 256u + threadIdx.x) >> 6;   // global wave id
    const unsigned nw = (gridDim.x * 256u) >> 6;
    const int d0 = lane * 8;

    for (unsigned j = gw; j < count; j += nw) {
        const unsigned e = list[j];
        const int op = e & 255;
        const int site = e >> 8;
        const int bI = site >> 10, nI = site & 1023;

        double wv[2][8];
        #pragma unroll
        for (int p = 0; p < 2; ++p) {
            const float* Wr = W + (size_t)(2 * op + p) * D_ + d0;
            const float4 a = *(const float4*)(Wr);
            const float4 b = *(const float4*)(Wr + 4);
            wv[p][0] = a.x; wv[p][1] = a.y; wv[p][2] = a.z; wv[p][3] = a.w;
            wv[p][4] = b.x; wv[p][5] = b.y; wv[p][6] = b.z; wv[p][7] = b.w;
        }

        double h[4][2];
        #pragma unroll
        for (int t = 0; t < 4; ++t) {
            const float* xr = x + (((size_t)t * 32 + bI) * 1024 + nI) * D_ + d0;
            const float4 a = *(const float4*)(xr);
            const float4 b = *(const float4*)(xr + 4);
            const double xv[8] = {(double)a.x, (double)a.y, (double)a.z, (double)a.w,
                                  (double)b.x, (double)b.y, (double)b.z, (double)b.w};
            #pragma unroll
            for (int p = 0; p < 2; ++p) {
                double s0 = 0, s1 = 0, s2 = 0, s3 = 0;
                s0 = fma(xv[0], wv[p][0], s0); s1 = fma(xv[1], wv[p][1], s1);
                s2 = fma(xv[2], wv[p][2], s2); s3 = fma(xv[3], wv[p][3], s3);
                s0 = fma(xv[4], wv[p][4], s0); s1 = fma(xv[5], wv[p][5], s1);
                s2 = fma(xv[6], wv[p][6], s2); s3 = fma(xv[7], wv[p][7], s3);
                double s = (s0 + s1) + (s2 + s3);
                #pragma unroll
                for (int off = 32; off > 0; off >>= 1)
                    s += __shfl_xor(s, off, 64);
                h[t][p] = s;
            }
        }

        double iv[2], ad[2];
        #pragma unroll
        for (int p = 0; p < 2; ++p) {
            const int c = 2 * op + p;
            iv[p] = (double)gamma[c] / sqrt((double)rvar[c] + 1e-5);
            ad[p] = (double)beta[c] - (double)rmean[c] * iv[p];
        }
        double v = 0.0;
        #pragma unroll
        for (int t = 0; t < 4; ++t) {
            const double h0 = h[t][0] * iv[0] + ad[0];
            const double h1 = h[t][1] * iv[1] + ad[1];
            const double m = fmax(h0, h1);
            v = (v + m) * 0.5;
            const bool sp = (v >= 1.0);
            if (lane == t)
                out[(((size_t)t * 32 + bI) * 1024 + nI) * 256 + op] = sp ? 1.0f : 0.0f;
            if (sp) v = 0.0;
        }
    }
}

// ---------------- fallback (round-1 exact f64 kernel) ----------------
constexpr int FB_SITES = 32, FB_ROWS = 128, FB_BN = 64, FB_BK = 16;

__global__ __launch_bounds__(256)
void snn_fused_f64(const float* __restrict__ x, const float* __restrict__ W,
                   const float* __restrict__ gamma, const float* __restrict__ beta,
                   const float* __restrict__ rmean, const float* __restrict__ rvar,
                   float* __restrict__ out)
{
    __shared__ float As[FB_BK][FB_ROWS];
    __shared__ float Bs[FB_BK][FB_BN];
    const int tid = threadIdx.x;
    const int tx = tid & 15, ty = tid >> 4;
    const int c0 = blockIdx.x * FB_BN;
    const int site_base = blockIdx.y * FB_SITES;
    const int b = site_base / N_, n0 = site_base % N_;
    const int lrow = tid >> 1, lk = (tid & 1) * 8;
    const int s_l = lrow >> 2, t_l = lrow & 3;
    const float* xrow = x + (size_t)((t_l * B_ + b) * N_ + (n0 + s_l)) * D_ + lk;
    const int wc = tid & 63, wk = (tid >> 6) * 4;
    const float* wrow = W + (size_t)(c0 + wc) * D_ + wk;
    double acc[8][4];
    #pragma unroll
    for (int i = 0; i < 8; ++i)
        #pragma unroll
        for (int j = 0; j < 4; ++j) acc[i][j] = 0.0;
    for (int k0 = 0; k0 < D_; k0 += FB_BK) {
        const float4 a0 = *(const float4*)(xrow + k0);
        const float4 a1 = *(const float4*)(xrow + k0 + 4);
        const float4 w4 = *(const float4*)(wrow + k0);
        As[lk + 0][lrow] = a0.x; As[lk + 1][lrow] = a0.y; As[lk + 2][lrow] = a0.z; As[lk + 3][lrow] = a0.w;
        As[lk + 4][lrow] = a1.x; As[lk + 5][lrow] = a1.y; As[lk + 6][lrow] = a1.z; As[lk + 7][lrow] = a1.w;
        Bs[wk + 0][wc] = w4.x; Bs[wk + 1][wc] = w4.y; Bs[wk + 2][wc] = w4.z; Bs[wk + 3][wc] = w4.w;
        __syncthreads();
        #pragma unroll
        for (int k = 0; k < FB_BK; ++k) {
            const float4 af0 = *(const float4*)&As[k][ty * 8];
            const float4 af1 = *(const float4*)&As[k][ty * 8 + 4];
            const float4 bf = *(const float4*)&Bs[k][tx * 4];
            const double ad[8] = {(double)af0.x, (double)af0.y, (double)af0.z, (double)af0.w,
                                  (double)af1.x, (double)af1.y, (double)af1.z, (double)af1.w};
            const double bd[4] = {(double)bf.x, (double)bf.y, (double)bf.z, (double)bf.w};
            #pragma unroll
            for (int i = 0; i < 8; ++i)
                #pragma unroll
                for (int j = 0; j < 4; ++j) acc[i][j] = fma(ad[i], bd[j], acc[i][j]);
        }
        __syncthreads();
    }
    double invd[4], addd[4];
    #pragma unroll
    for (int j = 0; j < 4; ++j) {
        const int c = c0 + tx * 4 + j;
        const double ivv = (double)gamma[c] / sqrt((double)rvar[c] + 1e-5);
        invd[j] = ivv; addd[j] = (double)beta[c] - (double)rmean[c] * ivv;
    }
    #pragma unroll
    for (int si = 0; si < 2; ++si) {
        const int n = n0 + ty * 2 + si;
        #pragma unroll
        for (int p = 0; p < 2; ++p) {
            const int op = (c0 >> 1) + tx * 2 + p;
            double v = 0.0;
            #pragma unroll
            for (int t = 0; t < 4; ++t) {
                const int i = si * 4 + t;
                const double h0 = acc[i][2 * p] * invd[2 * p] + addd[2 * p];
                const double h1 = acc[i][2 * p + 1] * invd[2 * p + 1] + addd[2 * p + 1];
                const double m = fmax(h0, h1);
                v = v + (m - v) * 0.5;
                const bool sp = (v >= 1.0);
                out[((size_t)(t * B_ + b) * N_ + n) * OP_ + op] = sp ? 1.0f : 0.0f;
                if (sp) v = 0.0;
            }
        }
    }
}

extern "C" void kernel_launch(void* const* d_in, const int* in_sizes, int n_in,
                              void* d_out, int out_size, void* d_ws, size_t ws_size,
                              hipStream_t stream)
{
    const float* x     = (const float*)d_in[0];
    const float* W     = (const float*)d_in[1];
    const float* gamma = (const float*)d_in[2];
    const float* beta  = (const float*)d_in[3];
    const float* rmean = (const float*)d_in[4];
    const float* rvar  = (const float*)d_in[5];
    float* out = (float*)d_out;

    if (ws_size < WS_NEED) {
        dim3 grid(O_ / FB_BN, (B_ * N_) / FB_SITES);
        snn_fused_f64<<<grid, dim3(256), 0, stream>>>(x, W, gamma, beta, rmean, rvar, out);
        return;
    }

    char* ws = (char*)d_ws;
    unsigned* cnt = (unsigned*)(ws + WS_CNT);
    unsigned short* wp = (unsigned short*)(ws + WS_WP);
    unsigned* list = (unsigned*)(ws + WS_LIST);

    k_wprep<<<128, 256, 0, stream>>>(W, wp, cnt);
    k_gemm<<<4096, 256, 2 * BUFSZ, stream>>>(x, wp, gamma, beta, rmean, rvar, out, cnt, list);
    k_repair<<<512, 256, 0, stream>>>(x, W, gamma, beta, rmean, rvar, out, cnt, list);
}